// Round 14
// baseline (240.570 us; speedup 1.0000x reference)
//
#include <hip/hip_runtime.h>

typedef __attribute__((ext_vector_type(8))) short bf16x8;     // 8 bf16 in 4 VGPRs
typedef __attribute__((ext_vector_type(4))) short bf16x4;     // 4 bf16 in 2 VGPRs
typedef __attribute__((ext_vector_type(8))) unsigned short u16x8;
typedef __attribute__((ext_vector_type(4))) float f32x4;

__device__ __forceinline__ unsigned short f2b(float f) {      // f32 -> bf16 RNE
  unsigned int u = __builtin_bit_cast(unsigned int, f);
  u += 0x7FFFu + ((u >> 16) & 1u);
  return (unsigned short)(u >> 16);
}
__device__ __forceinline__ float b2f(unsigned short h) {
  return __builtin_bit_cast(float, ((unsigned int)h) << 16);
}

__device__ __forceinline__ f32x4 mfma16x16x16(bf16x4 a, bf16x4 b, f32x4 c) {
#if __has_builtin(__builtin_amdgcn_mfma_f32_16x16x16bf16_1k)
  return __builtin_amdgcn_mfma_f32_16x16x16bf16_1k(a, b, c, 0, 0, 0);
#else
  asm volatile("v_mfma_f32_16x16x16_bf16 %0, %1, %2, %0" : "+v"(c) : "v"(a), "v"(b));
  return c;
#endif
}

#define AS1(p) (const __attribute__((address_space(1))) void*)(p)
#define AS3(p) (__attribute__((address_space(3))) void*)(p)

// ---------------- merged f32 -> bf16 convert (5 segments) ----------------
__device__ __forceinline__ void cvt8(const float* __restrict__ in,
                                     unsigned short* __restrict__ out,
                                     int i, float scale) {
  const float4* p = (const float4*)in + (size_t)i * 2;
  float4 a = p[0], b = p[1];
  u16x8 r;
  r[0] = f2b(a.x * scale); r[1] = f2b(a.y * scale);
  r[2] = f2b(a.z * scale); r[3] = f2b(a.w * scale);
  r[4] = f2b(b.x * scale); r[5] = f2b(b.y * scale);
  r[6] = f2b(b.z * scale); r[7] = f2b(b.w * scale);
  *((u16x8*)out + i) = r;
}

__global__ __launch_bounds__(256) void k_cvt_all(
    const float* __restrict__ x,  const float* __restrict__ Wq,
    const float* __restrict__ Wk, const float* __restrict__ Wv,
    const float* __restrict__ Wo, unsigned short* __restrict__ xb,
    unsigned short* __restrict__ wqkv, unsigned short* __restrict__ Wob,
    float sc) {
  int bid = blockIdx.x;                      // 9216 blocks total, 2048 elems each
  int tid = threadIdx.x;
  if (bid < 4096)      cvt8(x,  xb,             (bid        ) * 256 + tid, 1.f);
  else if (bid < 6144) cvt8(Wq, wqkv,           (bid - 4096) * 256 + tid, sc);
  else if (bid < 6656) cvt8(Wk, wqkv + 4194304, (bid - 6144) * 256 + tid, 1.f);
  else if (bid < 7168) cvt8(Wv, wqkv + 5242880, (bid - 6656) * 256 + tid, 1.f);
  else                 cvt8(Wo, Wob,            (bid - 7168) * 256 + tid, 1.f);
}

// ---------------- merged RoPE (q/k cols) + V transpose ----------------
__global__ __launch_bounds__(256) void k_post(unsigned short* __restrict__ qkv,
                                              const float* __restrict__ cosb,
                                              const float* __restrict__ sinb,
                                              unsigned short* __restrict__ vT) {
  __shared__ unsigned short tile[64][72];
  const int bid = blockIdx.x, t = threadIdx.x;
  if (bid < 2560) {
    int tid = bid * 256 + t;                 // 4096*20*8 = 655360
    int oct = tid & 7;
    int hd  = (tid >> 3) % 20;
    int s   = (tid >> 3) / 20;
    unsigned short* p1 = qkv + (size_t)s * 3072 + hd * 128 + oct * 8;
    unsigned short* p2 = p1 + 64;
    u16x8 a = *(const u16x8*)p1;
    u16x8 b = *(const u16x8*)p2;
    const float4* cp = (const float4*)(cosb + (size_t)s * 128 + oct * 8);
    const float4* sp = (const float4*)(sinb + (size_t)s * 128 + oct * 8);
    float4 c0 = cp[0], c1 = cp[1], s0 = sp[0], s1 = sp[1];
    float cs[8] = {c0.x,c0.y,c0.z,c0.w,c1.x,c1.y,c1.z,c1.w};
    float sn[8] = {s0.x,s0.y,s0.z,s0.w,s1.x,s1.y,s1.z,s1.w};
    u16x8 ra, rb;
#pragma unroll
    for (int j = 0; j < 8; ++j) {
      float av = b2f(a[j]), bv = b2f(b[j]);
      ra[j] = f2b(av * cs[j] - bv * sn[j]);
      rb[j] = f2b(bv * cs[j] + av * sn[j]);
    }
    *(u16x8*)p1 = ra;
    *(u16x8*)p2 = rb;
  } else {
    int idx = bid - 2560;                    // 512 tiles
    int bs = idx >> 3, bc = idx & 7;
#pragma unroll
    for (int i = 0; i < 2; ++i) {
      int c8 = t + 256 * i;                  // 0..511
      int row = c8 >> 3, cb = c8 & 7;
      u16x8 v = *(const u16x8*)(qkv + (size_t)(bs * 64 + row) * 3072 + 2560 + bc * 64 + cb * 8);
#pragma unroll
      for (int j = 0; j < 8; ++j) tile[row][cb * 8 + j] = v[j];
    }
    __syncthreads();
#pragma unroll
    for (int i = 0; i < 2; ++i) {
      int c8 = t + 256 * i;
      int crow = c8 >> 3, sb = c8 & 7;
      u16x8 v;
#pragma unroll
      for (int j = 0; j < 8; ++j) v[j] = tile[sb * 8 + j][crow];
      *(u16x8*)(vT + (size_t)(bc * 64 + crow) * 4096 + bs * 64 + sb * 8) = v;
    }
  }
}

// ---------------- GEMM C[M,N] = A[M,K] @ B[N,K]^T (bf16 in, bf16/f32 out) --
// XCD-swizzled block mapping: same-bn blocks (sharing a 512KB B-panel)
// cluster onto one XCD's L2. Requires gridDim.x % 8 == 0 (bijective).
template <int OUTF32>
__global__ __launch_bounds__(256) void k_gemm_bt(
    const unsigned short* __restrict__ A, const unsigned short* __restrict__ B,
    void* __restrict__ C, int K, int lda, int ldb, int ldc) {
  __shared__ unsigned short As[128 * 64];
  __shared__ unsigned short Bs[128 * 64];
  const int t = threadIdx.x;
  const int lane = t & 63, w = t >> 6;
  const int wm = w >> 1, wn = w & 1;
  const int o = blockIdx.x + blockIdx.y * gridDim.x;
  const int xcd = o & 7, j = o >> 3;
  const int per = gridDim.x >> 3;            // bn-panels per XCD
  const int bn = xcd * per + (j % per);
  const int bm = j / per;
  const unsigned short* Arow = A + (size_t)(bm * 128) * lda;
  const unsigned short* Brow = B + (size_t)(bn * 128) * ldb;

  f32x4 acc[4][4] = {};
  for (int kt = 0; kt < K; kt += 64) {
#pragma unroll
    for (int i = 0; i < 4; ++i) {
      int idx = i * 256 + t;
      int r = idx >> 3, blk = idx & 7;
      int sb = blk ^ (r & 7);
      __builtin_amdgcn_global_load_lds(AS1(Arow + (size_t)r * lda + kt + sb * 8),
                                       AS3(As + (i * 256 + w * 64) * 8), 16, 0, 0);
    }
#pragma unroll
    for (int i = 0; i < 4; ++i) {
      int idx = i * 256 + t;
      int r = idx >> 3, blk = idx & 7;
      int sb = blk ^ (r & 7);
      __builtin_amdgcn_global_load_lds(AS1(Brow + (size_t)r * ldb + kt + sb * 8),
                                       AS3(Bs + (i * 256 + w * 64) * 8), 16, 0, 0);
    }
    __syncthreads();
#pragma unroll
    for (int kk = 0; kk < 2; ++kk) {
      bf16x8 av[4], bv[4];
#pragma unroll
      for (int i = 0; i < 4; ++i) {
        int r = wm * 64 + i * 16 + (lane & 15);
        int off = (r * 128 + (kk * 32 + (lane >> 4) * 8) * 2) ^ ((r & 7) << 4);
        av[i] = *(const bf16x8*)((const char*)As + off);
      }
#pragma unroll
      for (int j2 = 0; j2 < 4; ++j2) {
        int r = wn * 64 + j2 * 16 + (lane & 15);
        int off = (r * 128 + (kk * 32 + (lane >> 4) * 8) * 2) ^ ((r & 7) << 4);
        bv[j2] = *(const bf16x8*)((const char*)Bs + off);
      }
#pragma unroll
      for (int i = 0; i < 4; ++i)
#pragma unroll
        for (int j2 = 0; j2 < 4; ++j2)
          acc[i][j2] = __builtin_amdgcn_mfma_f32_16x16x32_bf16(av[i], bv[j2], acc[i][j2], 0, 0, 0);
    }
    __syncthreads();
  }
#pragma unroll
  for (int i = 0; i < 4; ++i)
#pragma unroll
    for (int j2 = 0; j2 < 4; ++j2)
#pragma unroll
      for (int r = 0; r < 4; ++r) {
        int m = bm * 128 + wm * 64 + i * 16 + (lane >> 4) * 4 + r;
        int n = bn * 128 + wn * 64 + j2 * 16 + (lane & 15);
        float v = acc[i][j2][r];
        if (OUTF32) ((float*)C)[(size_t)m * ldc + n] = v;
        else        ((unsigned short*)C)[(size_t)m * ldc + n] = f2b(v);
      }
}

// ---------------- attention staging helpers (r4/r10-proven) ----------------
__device__ __forceinline__ void stage_k(const unsigned short* __restrict__ qk,
                                        unsigned short* __restrict__ dst,
                                        int kt, int g, int t, int w) {
#pragma unroll
  for (int i = 0; i < 4; ++i) {   // K tile [64 keys][128 d], swz low 3 bits of col16
    int idx = i * 256 + t;
    int r = idx >> 4, blk = idx & 15;
    int sb = (blk & 8) | ((blk ^ r) & 7);
    __builtin_amdgcn_global_load_lds(
        AS1(qk + (size_t)(kt * 64 + r) * 3072 + 2048 + g * 128 + sb * 8),
        AS3(dst + (i * 256 + w * 64) * 8), 16, 0, 0);
  }
}
__device__ __forceinline__ void stage_v(const unsigned short* __restrict__ vT,
                                        unsigned short* __restrict__ dst,
                                        int kt, int g, int t, int w) {
#pragma unroll
  for (int i = 0; i < 4; ++i) {   // V^T tile [128 d][64 keys]
    int idx = i * 256 + t;
    int r = idx >> 3, blk = idx & 7;
    int sb = blk ^ (r & 7);
    __builtin_amdgcn_global_load_lds(
        AS1(vT + (size_t)(g * 128 + r) * 4096 + kt * 64 + sb * 8),
        AS3(dst + (i * 256 + w * 64) * 8), 16, 0, 0);
  }
}

// ---------------- fused causal GQA flash attention ----------------
// r12/r13 structure (split-K groups, 2 heads/wave, XCD-clustered grid) with a
// TILE-LEVEL SOFTWARE PIPELINE: each barrier region executes
// QK(i+1) || softmax(i+1) || PV(i) — independent MFMA/VALU chains the
// scheduler can overlap (was serial QK->SM->PV). Buffers: K(j) in Ks[j&1],
// V(j) in Vs[j&1]; iteration i stages K(i+2) (K(i) dead) and V(i+1)
// (V(i-1) dead). One extra prologue barrier protects K(0) during peeled QK(0).
__global__ __launch_bounds__(512, 1) void k_attn(const unsigned short* __restrict__ qk,
                                                 const unsigned short* __restrict__ vT,
                                                 unsigned short* __restrict__ ctx) {
  __shared__ unsigned short Ks[2][2][64 * 128];   // [group][parity]
  __shared__ unsigned short Vs[2][2][64 * 128];
  const int b = blockIdx.x >> 3;             // 0..31
  const int hp = blockIdx.x & 7;             // head pair: heads 2hp, 2hp+1
  const int h0 = hp * 2, g = hp >> 1;
  const int t = threadIdx.x;                 // 0..511
  const int grp = t >> 8;                    // 0 = keys low half, 1 = high half
  const int tg = t & 255;                    // thread within group
  const int lane = t & 63, w4 = (t >> 6) & 3;
  const int l15 = lane & 15, lq = lane >> 4;

  float* ol = (float*)&Ks[0][0][0];          // 64KB combine scratch (post-loop)
  float* ll = (float*)&Vs[0][0][0];          // lsum scratch (post-loop)

  for (int ph = 0; ph < 2; ++ph) {
    const int qt = ph ? 63 - b : b;
    const int ntot = qt + 1;
    const int m = (ntot + 1) >> 1;           // group A tiles [0,m)
    const int nB = ntot - m;                 // group B tiles [m,ntot), nB <= m
    const int kbase = grp ? m : 0;
    const int ntile = grp ? nB : m;
    const int qg = qt * 64 + w4 * 16 + l15;  // this lane's softmax q-row

    bf16x8 aq0[4], aq1[4];        // Q fragments, both heads
    {
      const unsigned short* qb =
          qk + (size_t)(qt * 64 + w4 * 16 + l15) * 3072 + h0 * 128 + lq * 8;
#pragma unroll
      for (int sl = 0; sl < 4; ++sl) {
        aq0[sl] = *(const bf16x8*)(qb + sl * 32);
        aq1[sl] = *(const bf16x8*)(qb + 128 + sl * 32);
      }
    }
    f32x4 o0[8] = {}, o1[8] = {};
    float lsum0 = 0.f, lsum1 = 0.f;
    bf16x4 paC0[4], paC1[4], paN0[4], paN1[4];

    unsigned short* K0 = Ks[grp][0];
    unsigned short* K1 = Ks[grp][1];
    unsigned short* V0 = Vs[grp][0];
    unsigned short* V1 = Vs[grp][1];

    // QK(kt) -> softmax -> pa (dest arrays given); accumulates lsum
    auto qk_sm = [&](const unsigned short* Kb, int ktg, bf16x4* pA0, bf16x4* pA1) {
      f32x4 st0[4] = {}, st1[4] = {};
      __builtin_amdgcn_s_setprio(1);
#pragma unroll
      for (int sl = 0; sl < 4; ++sl)
#pragma unroll
        for (int nt = 0; nt < 4; ++nt) {
          int key = nt * 16 + l15;
          int off = (key * 256 + sl * 64 + lq * 16) ^ ((key & 7) << 4);
          bf16x8 bk = *(const bf16x8*)((const char*)Kb + off);
          st0[nt] = __builtin_amdgcn_mfma_f32_16x16x32_bf16(bk, aq0[sl], st0[nt], 0, 0, 0);
          st1[nt] = __builtin_amdgcn_mfma_f32_16x16x32_bf16(bk, aq1[sl], st1[nt], 0, 0, 0);
        }
      __builtin_amdgcn_s_setprio(0);
      const bool maskT = (ktg == qt);
#pragma unroll
      for (int nt = 0; nt < 4; ++nt)
#pragma unroll
        for (int r = 0; r < 4; ++r) {
          float p0 = __builtin_amdgcn_exp2f(st0[nt][r]);
          float p1 = __builtin_amdgcn_exp2f(st1[nt][r]);
          if (maskT) {
            int key = ktg * 64 + nt * 16 + lq * 4 + r;
            if (key > qg) { p0 = 0.f; p1 = 0.f; }
          }
          lsum0 += p0; lsum1 += p1;
          unsigned int u0 = __builtin_bit_cast(unsigned int, p0) + 0x8000u;
          unsigned int u1 = __builtin_bit_cast(unsigned int, p1) + 0x8000u;
          pA0[nt][r] = (short)(u0 >> 16);
          pA1[nt][r] = (short)(u1 >> 16);
        }
    };
    auto pv = [&](const unsigned short* Vb, const bf16x4* pA0, const bf16x4* pA1) {
      __builtin_amdgcn_s_setprio(1);
#pragma unroll
      for (int nt = 0; nt < 4; ++nt)
#pragma unroll
        for (int dt = 0; dt < 8; ++dt) {
          int d = dt * 16 + l15;
          int off = (d * 128 + nt * 32 + lq * 8) ^ ((d & 7) << 4);
          bf16x4 vv = *(const bf16x4*)((const char*)Vb + off);
          o0[dt] = mfma16x16x16(pA0[nt], vv, o0[dt]);
          o1[dt] = mfma16x16x16(pA1[nt], vv, o1[dt]);
        }
      __builtin_amdgcn_s_setprio(0);
    };

    // ---- prologue: stage K0,V0,K1; peel QK(0)+softmax(0) ----
    if (ntile > 0) {
      stage_k(qk, K0, kbase, g, tg, w4);
      stage_v(vT, V0, kbase, g, tg, w4);
    }
    if (ntile > 1) stage_k(qk, K1, kbase + 1, g, tg, w4);
    asm volatile("s_waitcnt vmcnt(0)" ::: "memory");
    __builtin_amdgcn_s_barrier();
    if (ntile > 0) qk_sm(K0, kbase, paC0, paC1);
    __builtin_amdgcn_s_barrier();            // protect K(0) from iter-0 staging

    // ---- pipelined main loop: region = QK(i+1) || SM(i+1) || PV(i) ----
    for (int i = 0; i < m; ++i) {
      const int cur = i & 1;
      unsigned short* Kcur = cur ? K1 : K0;  // holds K(i): dead -> stage target
      unsigned short* Knxt = cur ? K0 : K1;  // holds K(i+1)
      unsigned short* Vcur = cur ? V1 : V0;  // holds V(i)
      unsigned short* Vnxt = cur ? V0 : V1;  // stage target V(i+1)
      if (i + 2 < ntile) stage_k(qk, Kcur, kbase + i + 2, g, tg, w4);
      if (i + 1 < ntile) stage_v(vT, Vnxt, kbase + i + 1, g, tg, w4);
      if (i + 1 < ntile) qk_sm(Knxt, kbase + i + 1, paN0, paN1);
      if (i < ntile)     pv(Vcur, paC0, paC1);
      if (i + 1 < ntile) {
#pragma unroll
        for (int nt = 0; nt < 4; ++nt) { paC0[nt] = paN0[nt]; paC1[nt] = paN1[nt]; }
      }
      asm volatile("s_waitcnt vmcnt(0)" ::: "memory");
      __builtin_amdgcn_s_barrier();
    }

    // ---- combine: O = (O_A + O_B) / (l_A + l_B) via LDS ----
    float f0 = lsum0, f1 = lsum1;            // reduce partial row sums
    f0 += __shfl_xor(f0, 16); f0 += __shfl_xor(f0, 32);
    f1 += __shfl_xor(f1, 16); f1 += __shfl_xor(f1, 32);

    if (grp == 1) {                          // B publishes partials
#pragma unroll
      for (int dt = 0; dt < 8; ++dt)
#pragma unroll
        for (int r = 0; r < 4; ++r) {
          ol[(dt * 4 + r) * 256 + tg]        = o0[dt][r];
          ol[(32 + dt * 4 + r) * 256 + tg]   = o1[dt][r];
        }
      if (lq == 0) {
        ll[w4 * 16 + l15]      = f0;
        ll[64 + w4 * 16 + l15] = f1;
      }
    }
    __builtin_amdgcn_s_barrier();
    if (grp == 0) {                          // A combines, normalizes, stores
#pragma unroll
      for (int dt = 0; dt < 8; ++dt)
#pragma unroll
        for (int r = 0; r < 4; ++r) {
          o0[dt][r] += ol[(dt * 4 + r) * 256 + tg];
          o1[dt][r] += ol[(32 + dt * 4 + r) * 256 + tg];
        }
      f0 += ll[w4 * 16 + l15];
      f1 += ll[64 + w4 * 16 + l15];
      float iq0[4], iq1[4];
#pragma unroll
      for (int r = 0; r < 4; ++r) {
        iq0[r] = 1.f / __shfl(f0, lq * 4 + r);
        iq1[r] = 1.f / __shfl(f1, lq * 4 + r);
      }
#pragma unroll
      for (int dt = 0; dt < 8; ++dt)
#pragma unroll
        for (int r = 0; r < 4; ++r) {
          int q = qt * 64 + w4 * 16 + lq * 4 + r;
          int c = h0 * 128 + dt * 16 + l15;
          ctx[(size_t)q * 2048 + c]       = f2b(o0[dt][r] * iq0[r]);
          ctx[(size_t)q * 2048 + c + 128] = f2b(o1[dt][r] * iq1[r]);
        }
    }
    __builtin_amdgcn_s_barrier();            // protect LDS for next phase
  }
}

// ---------------- host ----------------
extern "C" void kernel_launch(void* const* d_in, const int* in_sizes, int n_in,
                              void* d_out, int out_size, void* d_ws, size_t ws_size,
                              hipStream_t stream) {
  const float* x    = (const float*)d_in[0];
  const float* cosb = (const float*)d_in[2];
  const float* sinb = (const float*)d_in[3];
  const float* Wq   = (const float*)d_in[4];
  const float* Wk   = (const float*)d_in[5];
  const float* Wv   = (const float*)d_in[6];
  const float* Wo   = (const float*)d_in[7];

  char* p = (char*)d_ws;
  unsigned short* xb   = (unsigned short*)p; p += (size_t)8388608 * 2;   // x bf16
  unsigned short* wqkv = (unsigned short*)p; p += (size_t)6291456 * 2;   // [3072][2048]
  unsigned short* Wob  = (unsigned short*)p; p += (size_t)4194304 * 2;
  unsigned short* qkvb = (unsigned short*)p; p += (size_t)4096 * 3072 * 2;
  unsigned short* vTb  = (unsigned short*)p; p += (size_t)512 * 4096 * 2;
  unsigned short* ctx  = (unsigned short*)p; p += (size_t)4096 * 2048 * 2;
  if (ws_size < (size_t)(p - (char*)d_ws)) return;

  const float SC = 0.12751741f;   // (1/sqrt(128)) * log2(e), folded into Wq

  k_cvt_all<<<9216, 256, 0, stream>>>(x, Wq, Wk, Wv, Wo, xb, wqkv, Wob, SC);

  // qkv = x @ [Wq;Wk;Wv]^T  -> [4096][3072] (q:0-2047, k:2048-2559, v:2560-3071)
  k_gemm_bt<0><<<dim3(24, 32), 256, 0, stream>>>(xb, wqkv, qkvb, 2048, 2048, 2048, 3072);

  k_post<<<3072, 256, 0, stream>>>(qkvb, cosb, sinb, vTb);

  k_attn<<<256, 512, 0, stream>>>(qkvb, vTb, ctx);

  k_gemm_bt<1><<<dim3(16, 32), 256, 0, stream>>>(ctx, Wob, d_out, 2048, 2048, 2048, 2048);
}

// Round 15
// 237.165 us; speedup vs baseline: 1.0144x; 1.0144x over previous
//
#include <hip/hip_runtime.h>

typedef __attribute__((ext_vector_type(8))) short bf16x8;     // 8 bf16 in 4 VGPRs
typedef __attribute__((ext_vector_type(4))) short bf16x4;     // 4 bf16 in 2 VGPRs
typedef __attribute__((ext_vector_type(8))) unsigned short u16x8;
typedef __attribute__((ext_vector_type(4))) float f32x4;

__device__ __forceinline__ unsigned short f2b(float f) {      // f32 -> bf16 RNE
  unsigned int u = __builtin_bit_cast(unsigned int, f);
  u += 0x7FFFu + ((u >> 16) & 1u);
  return (unsigned short)(u >> 16);
}
__device__ __forceinline__ float b2f(unsigned short h) {
  return __builtin_bit_cast(float, ((unsigned int)h) << 16);
}

__device__ __forceinline__ f32x4 mfma16x16x16(bf16x4 a, bf16x4 b, f32x4 c) {
#if __has_builtin(__builtin_amdgcn_mfma_f32_16x16x16bf16_1k)
  return __builtin_amdgcn_mfma_f32_16x16x16bf16_1k(a, b, c, 0, 0, 0);
#else
  asm volatile("v_mfma_f32_16x16x16_bf16 %0, %1, %2, %0" : "+v"(c) : "v"(a), "v"(b));
  return c;
#endif
}

#define AS1(p) (const __attribute__((address_space(1))) void*)(p)
#define AS3(p) (__attribute__((address_space(3))) void*)(p)

// ---------------- merged f32 -> bf16 convert (5 segments) ----------------
__device__ __forceinline__ void cvt8(const float* __restrict__ in,
                                     unsigned short* __restrict__ out,
                                     int i, float scale) {
  const float4* p = (const float4*)in + (size_t)i * 2;
  float4 a = p[0], b = p[1];
  u16x8 r;
  r[0] = f2b(a.x * scale); r[1] = f2b(a.y * scale);
  r[2] = f2b(a.z * scale); r[3] = f2b(a.w * scale);
  r[4] = f2b(b.x * scale); r[5] = f2b(b.y * scale);
  r[6] = f2b(b.z * scale); r[7] = f2b(b.w * scale);
  *((u16x8*)out + i) = r;
}

__global__ __launch_bounds__(256) void k_cvt_all(
    const float* __restrict__ x,  const float* __restrict__ Wq,
    const float* __restrict__ Wk, const float* __restrict__ Wv,
    const float* __restrict__ Wo, unsigned short* __restrict__ xb,
    unsigned short* __restrict__ wqkv, unsigned short* __restrict__ Wob,
    float sc) {
  int bid = blockIdx.x;                      // 9216 blocks total, 2048 elems each
  int tid = threadIdx.x;
  if (bid < 4096)      cvt8(x,  xb,             (bid        ) * 256 + tid, 1.f);
  else if (bid < 6144) cvt8(Wq, wqkv,           (bid - 4096) * 256 + tid, sc);
  else if (bid < 6656) cvt8(Wk, wqkv + 4194304, (bid - 6144) * 256 + tid, 1.f);
  else if (bid < 7168) cvt8(Wv, wqkv + 5242880, (bid - 6656) * 256 + tid, 1.f);
  else                 cvt8(Wo, Wob,            (bid - 7168) * 256 + tid, 1.f);
}

// ---------------- merged RoPE (q/k cols) + V transpose ----------------
__global__ __launch_bounds__(256) void k_post(unsigned short* __restrict__ qkv,
                                              const float* __restrict__ cosb,
                                              const float* __restrict__ sinb,
                                              unsigned short* __restrict__ vT) {
  __shared__ unsigned short tile[64][72];
  const int bid = blockIdx.x, t = threadIdx.x;
  if (bid < 2560) {
    int tid = bid * 256 + t;                 // 4096*20*8 = 655360
    int oct = tid & 7;
    int hd  = (tid >> 3) % 20;
    int s   = (tid >> 3) / 20;
    unsigned short* p1 = qkv + (size_t)s * 3072 + hd * 128 + oct * 8;
    unsigned short* p2 = p1 + 64;
    u16x8 a = *(const u16x8*)p1;
    u16x8 b = *(const u16x8*)p2;
    const float4* cp = (const float4*)(cosb + (size_t)s * 128 + oct * 8);
    const float4* sp = (const float4*)(sinb + (size_t)s * 128 + oct * 8);
    float4 c0 = cp[0], c1 = cp[1], s0 = sp[0], s1 = sp[1];
    float cs[8] = {c0.x,c0.y,c0.z,c0.w,c1.x,c1.y,c1.z,c1.w};
    float sn[8] = {s0.x,s0.y,s0.z,s0.w,s1.x,s1.y,s1.z,s1.w};
    u16x8 ra, rb;
#pragma unroll
    for (int j = 0; j < 8; ++j) {
      float av = b2f(a[j]), bv = b2f(b[j]);
      ra[j] = f2b(av * cs[j] - bv * sn[j]);
      rb[j] = f2b(bv * cs[j] + av * sn[j]);
    }
    *(u16x8*)p1 = ra;
    *(u16x8*)p2 = rb;
  } else {
    int idx = bid - 2560;                    // 512 tiles
    int bs = idx >> 3, bc = idx & 7;
#pragma unroll
    for (int i = 0; i < 2; ++i) {
      int c8 = t + 256 * i;                  // 0..511
      int row = c8 >> 3, cb = c8 & 7;
      u16x8 v = *(const u16x8*)(qkv + (size_t)(bs * 64 + row) * 3072 + 2560 + bc * 64 + cb * 8);
#pragma unroll
      for (int j = 0; j < 8; ++j) tile[row][cb * 8 + j] = v[j];
    }
    __syncthreads();
#pragma unroll
    for (int i = 0; i < 2; ++i) {
      int c8 = t + 256 * i;
      int crow = c8 >> 3, sb = c8 & 7;
      u16x8 v;
#pragma unroll
      for (int j = 0; j < 8; ++j) v[j] = tile[sb * 8 + j][crow];
      *(u16x8*)(vT + (size_t)(bc * 64 + crow) * 4096 + bs * 64 + sb * 8) = v;
    }
  }
}

// ---------------- GEMM C[M,N] = A[M,K] @ B[N,K]^T (bf16 in, bf16/f32 out) --
// Plain block mapping (XCD swizzle removed: working sets are L3-resident,
// swizzle measured ~0 here and costs ~2% when L3-fit per guide m160).
template <int OUTF32>
__global__ __launch_bounds__(256) void k_gemm_bt(
    const unsigned short* __restrict__ A, const unsigned short* __restrict__ B,
    void* __restrict__ C, int K, int lda, int ldb, int ldc) {
  __shared__ unsigned short As[128 * 64];
  __shared__ unsigned short Bs[128 * 64];
  const int t = threadIdx.x;
  const int lane = t & 63, w = t >> 6;
  const int wm = w >> 1, wn = w & 1;
  const int bn = blockIdx.x, bm = blockIdx.y;
  const unsigned short* Arow = A + (size_t)(bm * 128) * lda;
  const unsigned short* Brow = B + (size_t)(bn * 128) * ldb;

  f32x4 acc[4][4] = {};
  for (int kt = 0; kt < K; kt += 64) {
#pragma unroll
    for (int i = 0; i < 4; ++i) {
      int idx = i * 256 + t;
      int r = idx >> 3, blk = idx & 7;
      int sb = blk ^ (r & 7);
      __builtin_amdgcn_global_load_lds(AS1(Arow + (size_t)r * lda + kt + sb * 8),
                                       AS3(As + (i * 256 + w * 64) * 8), 16, 0, 0);
    }
#pragma unroll
    for (int i = 0; i < 4; ++i) {
      int idx = i * 256 + t;
      int r = idx >> 3, blk = idx & 7;
      int sb = blk ^ (r & 7);
      __builtin_amdgcn_global_load_lds(AS1(Brow + (size_t)r * ldb + kt + sb * 8),
                                       AS3(Bs + (i * 256 + w * 64) * 8), 16, 0, 0);
    }
    __syncthreads();
#pragma unroll
    for (int kk = 0; kk < 2; ++kk) {
      bf16x8 av[4], bv[4];
#pragma unroll
      for (int i = 0; i < 4; ++i) {
        int r = wm * 64 + i * 16 + (lane & 15);
        int off = (r * 128 + (kk * 32 + (lane >> 4) * 8) * 2) ^ ((r & 7) << 4);
        av[i] = *(const bf16x8*)((const char*)As + off);
      }
#pragma unroll
      for (int j2 = 0; j2 < 4; ++j2) {
        int r = wn * 64 + j2 * 16 + (lane & 15);
        int off = (r * 128 + (kk * 32 + (lane >> 4) * 8) * 2) ^ ((r & 7) << 4);
        bv[j2] = *(const bf16x8*)((const char*)Bs + off);
      }
#pragma unroll
      for (int i = 0; i < 4; ++i)
#pragma unroll
        for (int j2 = 0; j2 < 4; ++j2)
          acc[i][j2] = __builtin_amdgcn_mfma_f32_16x16x32_bf16(av[i], bv[j2], acc[i][j2], 0, 0, 0);
    }
    __syncthreads();
  }
#pragma unroll
  for (int i = 0; i < 4; ++i)
#pragma unroll
    for (int j2 = 0; j2 < 4; ++j2)
#pragma unroll
      for (int r = 0; r < 4; ++r) {
        int m = bm * 128 + wm * 64 + i * 16 + (lane >> 4) * 4 + r;
        int n = bn * 128 + wn * 64 + j2 * 16 + (lane & 15);
        float v = acc[i][j2][r];
        if (OUTF32) ((float*)C)[(size_t)m * ldc + n] = v;
        else        ((unsigned short*)C)[(size_t)m * ldc + n] = f2b(v);
      }
}

// ---------------- attention staging helpers (r4/r10-proven) ----------------
__device__ __forceinline__ void stage_k(const unsigned short* __restrict__ qk,
                                        unsigned short* __restrict__ dst,
                                        int kt, int g, int t, int w) {
#pragma unroll
  for (int i = 0; i < 4; ++i) {   // K tile [64 keys][128 d], swz low 3 bits of col16
    int idx = i * 256 + t;
    int r = idx >> 4, blk = idx & 15;
    int sb = (blk & 8) | ((blk ^ r) & 7);
    __builtin_amdgcn_global_load_lds(
        AS1(qk + (size_t)(kt * 64 + r) * 3072 + 2048 + g * 128 + sb * 8),
        AS3(dst + (i * 256 + w * 64) * 8), 16, 0, 0);
  }
}
__device__ __forceinline__ void stage_v(const unsigned short* __restrict__ vT,
                                        unsigned short* __restrict__ dst,
                                        int kt, int g, int t, int w) {
#pragma unroll
  for (int i = 0; i < 4; ++i) {   // V^T tile [128 d][64 keys]
    int idx = i * 256 + t;
    int r = idx >> 3, blk = idx & 7;
    int sb = blk ^ (r & 7);
    __builtin_amdgcn_global_load_lds(
        AS1(vT + (size_t)(g * 128 + r) * 4096 + kt * 64 + sb * 8),
        AS3(dst + (i * 256 + w * 64) * 8), 16, 0, 0);
  }
}

// ---------------- fused causal GQA flash attention (split-K in block) ------
// r13 structure (split-K groups, 2 heads/wave, XCD-clustered 1D grid) with
// COUNTED-vmcnt split waits (T4): stage K(i+1) -> vmcnt(8) [K(i) older than
// the 8 newest K(i+1)+V(i) => landed] + barrier -> QK+SM -> stage V(i+1) ->
// vmcnt(8) [V(i) older than K(i+1)+V(i+1)] + barrier -> PV. Loads stay in
// flight across barriers; tail iterations use exact counts (4/0).
__global__ __launch_bounds__(512, 1) void k_attn(const unsigned short* __restrict__ qk,
                                                 const unsigned short* __restrict__ vT,
                                                 unsigned short* __restrict__ ctx) {
  __shared__ unsigned short Ks[2][2][64 * 128];   // [group][parity]
  __shared__ unsigned short Vs[2][2][64 * 128];
  const int b = blockIdx.x >> 3;             // 0..31
  const int hp = blockIdx.x & 7;             // head pair: heads 2hp, 2hp+1
  const int h0 = hp * 2, g = hp >> 1;
  const int t = threadIdx.x;                 // 0..511
  const int grp = t >> 8;                    // 0 = keys low half, 1 = high half
  const int tg = t & 255;                    // thread within group
  const int lane = t & 63, w4 = (t >> 6) & 3;
  const int l15 = lane & 15, lq = lane >> 4;

  float* ol = (float*)&Ks[0][0][0];          // 64KB combine scratch (post-loop)
  float* ll = (float*)&Vs[0][0][0];          // lsum scratch (post-loop)

  for (int ph = 0; ph < 2; ++ph) {
    const int qt = ph ? 63 - b : b;
    const int ntot = qt + 1;
    const int m = (ntot + 1) >> 1;           // group A tiles [0,m)
    const int nB = ntot - m;                 // group B tiles [m,ntot), nB <= m
    const int kbase = grp ? m : 0;
    const int ntile = grp ? nB : m;
    const int qg = qt * 64 + w4 * 16 + l15;  // this lane's softmax q-row

    bf16x8 aq0[4], aq1[4];        // Q fragments, both heads
    {
      const unsigned short* qb =
          qk + (size_t)(qt * 64 + w4 * 16 + l15) * 3072 + h0 * 128 + lq * 8;
#pragma unroll
      for (int sl = 0; sl < 4; ++sl) {
        aq0[sl] = *(const bf16x8*)(qb + sl * 32);
        aq1[sl] = *(const bf16x8*)(qb + 128 + sl * 32);
      }
    }
    f32x4 o0[8] = {}, o1[8] = {};
    float lsum0 = 0.f, lsum1 = 0.f;

    unsigned short* K0 = Ks[grp][0];
    unsigned short* K1 = Ks[grp][1];
    unsigned short* V0 = Vs[grp][0];
    unsigned short* V1 = Vs[grp][1];

    // prologue: stage my first tile, K first then V (order matters for counts)
    if (ntile > 0) {
      stage_k(qk, K0, kbase, g, tg, w4);
      stage_v(vT, V0, kbase, g, tg, w4);
    }

    for (int i = 0; i < m; ++i) {            // both groups run m iterations
      const int cur = i & 1;
      const unsigned short* Kb = cur ? K1 : K0;
      const unsigned short* Vb = cur ? V1 : V0;
      const bool pre = (i + 1 < ntile);
      const int kt = kbase + i;
      const bool live = (i < ntile);
      const bool maskT = live && (kt == qt);

      if (pre) stage_k(qk, cur ? K0 : K1, kbase + i + 1, g, tg, w4);
      // K(i) is older than the <=8 newest loads (K(i+1) 4 + V(i) 4)
      if (pre) asm volatile("s_waitcnt vmcnt(8)" ::: "memory");
      else     asm volatile("s_waitcnt vmcnt(4)" ::: "memory");
      __builtin_amdgcn_s_barrier();

      // ---- S^T = K @ Q^T for both heads (shared K read) ----
      f32x4 st0[4] = {}, st1[4] = {};
      if (live) {
        __builtin_amdgcn_s_setprio(1);
#pragma unroll
        for (int sl = 0; sl < 4; ++sl)
#pragma unroll
          for (int nt = 0; nt < 4; ++nt) {
            int key = nt * 16 + l15;
            int off = (key * 256 + sl * 64 + lq * 16) ^ ((key & 7) << 4);
            bf16x8 bk = *(const bf16x8*)((const char*)Kb + off);
            st0[nt] = __builtin_amdgcn_mfma_f32_16x16x32_bf16(bk, aq0[sl], st0[nt], 0, 0, 0);
            st1[nt] = __builtin_amdgcn_mfma_f32_16x16x32_bf16(bk, aq1[sl], st1[nt], 0, 0, 0);
          }
        __builtin_amdgcn_s_setprio(0);
      }
      // ---- streaming softmax, in-register (Q pre-scaled, no max) ----
      bf16x4 pa0[4], pa1[4];
      if (live) {
#pragma unroll
        for (int nt = 0; nt < 4; ++nt)
#pragma unroll
          for (int r = 0; r < 4; ++r) {
            float p0 = __builtin_amdgcn_exp2f(st0[nt][r]);
            float p1 = __builtin_amdgcn_exp2f(st1[nt][r]);
            if (maskT) {
              int key = kt * 64 + nt * 16 + lq * 4 + r;
              if (key > qg) { p0 = 0.f; p1 = 0.f; }
            }
            lsum0 += p0; lsum1 += p1;
            unsigned int u0 = __builtin_bit_cast(unsigned int, p0) + 0x8000u;
            unsigned int u1 = __builtin_bit_cast(unsigned int, p1) + 0x8000u;
            pa0[nt][r] = (short)(u0 >> 16);
            pa1[nt][r] = (short)(u1 >> 16);
          }
      }

      if (pre) stage_v(vT, cur ? V0 : V1, kbase + i + 1, g, tg, w4);
      // V(i) is older than the <=8 newest loads (K(i+1) 4 + V(i+1) 4)
      if (pre) asm volatile("s_waitcnt vmcnt(8)" ::: "memory");
      else     asm volatile("s_waitcnt vmcnt(0)" ::: "memory");
      __builtin_amdgcn_s_barrier();

      // ---- O += P @ V for both heads (shared V read) ----
      if (live) {
        __builtin_amdgcn_s_setprio(1);
#pragma unroll
        for (int nt = 0; nt < 4; ++nt)
#pragma unroll
          for (int dt = 0; dt < 8; ++dt) {
            int d = dt * 16 + l15;
            int off = (d * 128 + nt * 32 + lq * 8) ^ ((d & 7) << 4);
            bf16x4 vv = *(const bf16x4*)((const char*)Vb + off);
            o0[dt] = mfma16x16x16(pa0[nt], vv, o0[dt]);
            o1[dt] = mfma16x16x16(pa1[nt], vv, o1[dt]);
          }
        __builtin_amdgcn_s_setprio(0);
      }
    }
    __builtin_amdgcn_s_barrier();            // all PV reads done before combine

    // ---- combine: O = (O_A + O_B) / (l_A + l_B) via LDS ----
    float f0 = lsum0, f1 = lsum1;            // reduce partial row sums
    f0 += __shfl_xor(f0, 16); f0 += __shfl_xor(f0, 32);
    f1 += __shfl_xor(f1, 16); f1 += __shfl_xor(f1, 32);

    if (grp == 1) {                          // B publishes partials
#pragma unroll
      for (int dt = 0; dt < 8; ++dt)
#pragma unroll
        for (int r = 0; r < 4; ++r) {
          ol[(dt * 4 + r) * 256 + tg]        = o0[dt][r];
          ol[(32 + dt * 4 + r) * 256 + tg]   = o1[dt][r];
        }
      if (lq == 0) {
        ll[w4 * 16 + l15]      = f0;
        ll[64 + w4 * 16 + l15] = f1;
      }
    }
    __builtin_amdgcn_s_barrier();
    if (grp == 0) {                          // A combines, normalizes, stores
#pragma unroll
      for (int dt = 0; dt < 8; ++dt)
#pragma unroll
        for (int r = 0; r < 4; ++r) {
          o0[dt][r] += ol[(dt * 4 + r) * 256 + tg];
          o1[dt][r] += ol[(32 + dt * 4 + r) * 256 + tg];
        }
      f0 += ll[w4 * 16 + l15];
      f1 += ll[64 + w4 * 16 + l15];
      float iq0[4], iq1[4];
#pragma unroll
      for (int r = 0; r < 4; ++r) {
        iq0[r] = 1.f / __shfl(f0, lq * 4 + r);
        iq1[r] = 1.f / __shfl(f1, lq * 4 + r);
      }
#pragma unroll
      for (int dt = 0; dt < 8; ++dt)
#pragma unroll
        for (int r = 0; r < 4; ++r) {
          int q = qt * 64 + w4 * 16 + lq * 4 + r;
          int c = h0 * 128 + dt * 16 + l15;
          ctx[(size_t)q * 2048 + c]       = f2b(o0[dt][r] * iq0[r]);
          ctx[(size_t)q * 2048 + c + 128] = f2b(o1[dt][r] * iq1[r]);
        }
    }
    __builtin_amdgcn_s_barrier();            // protect LDS for next phase
  }
}

// ---------------- host ----------------
extern "C" void kernel_launch(void* const* d_in, const int* in_sizes, int n_in,
                              void* d_out, int out_size, void* d_ws, size_t ws_size,
                              hipStream_t stream) {
  const float* x    = (const float*)d_in[0];
  const float* cosb = (const float*)d_in[2];
  const float* sinb = (const float*)d_in[3];
  const float* Wq   = (const float*)d_in[4];
  const float* Wk   = (const float*)d_in[5];
  const float* Wv   = (const float*)d_in[6];
  const float* Wo   = (const float*)d_in[7];

  char* p = (char*)d_ws;
  unsigned short* xb   = (unsigned short*)p; p += (size_t)8388608 * 2;   // x bf16
  unsigned short* wqkv = (unsigned short*)p; p += (size_t)6291456 * 2;   // [3072][2048]
  unsigned short* Wob  = (unsigned short*)p; p += (size_t)4194304 * 2;
  unsigned short* qkvb = (unsigned short*)p; p += (size_t)4096 * 3072 * 2;
  unsigned short* vTb  = (unsigned short*)p; p += (size_t)512 * 4096 * 2;
  unsigned short* ctx  = (unsigned short*)p; p += (size_t)4096 * 2048 * 2;
  if (ws_size < (size_t)(p - (char*)d_ws)) return;

  const float SC = 0.12751741f;   // (1/sqrt(128)) * log2(e), folded into Wq

  k_cvt_all<<<9216, 256, 0, stream>>>(x, Wq, Wk, Wv, Wo, xb, wqkv, Wob, SC);

  // qkv = x @ [Wq;Wk;Wv]^T  -> [4096][3072] (q:0-2047, k:2048-2559, v:2560-3071)
  k_gemm_bt<0><<<dim3(24, 32), 256, 0, stream>>>(xb, wqkv, qkvb, 2048, 2048, 2048, 3072);

  k_post<<<3072, 256, 0, stream>>>(qkvb, cosb, sinb, vTb);

  k_attn<<<256, 512, 0, stream>>>(qkvb, vTb, ctx);

  k_gemm_bt<1><<<dim3(16, 32), 256, 0, stream>>>(ctx, Wob, d_out, 2048, 2048, 2048, 2048);
}

// Round 16
// 232.565 us; speedup vs baseline: 1.0344x; 1.0198x over previous
//
#include <hip/hip_runtime.h>

typedef __attribute__((ext_vector_type(8))) short bf16x8;     // 8 bf16 in 4 VGPRs
typedef __attribute__((ext_vector_type(4))) short bf16x4;     // 4 bf16 in 2 VGPRs
typedef __attribute__((ext_vector_type(8))) unsigned short u16x8;
typedef __attribute__((ext_vector_type(4))) float f32x4;

__device__ __forceinline__ unsigned short f2b(float f) {      // f32 -> bf16 RNE
  unsigned int u = __builtin_bit_cast(unsigned int, f);
  u += 0x7FFFu + ((u >> 16) & 1u);
  return (unsigned short)(u >> 16);
}
__device__ __forceinline__ float b2f(unsigned short h) {
  return __builtin_bit_cast(float, ((unsigned int)h) << 16);
}

__device__ __forceinline__ f32x4 mfma16x16x16(bf16x4 a, bf16x4 b, f32x4 c) {
#if __has_builtin(__builtin_amdgcn_mfma_f32_16x16x16bf16_1k)
  return __builtin_amdgcn_mfma_f32_16x16x16bf16_1k(a, b, c, 0, 0, 0);
#else
  asm volatile("v_mfma_f32_16x16x16_bf16 %0, %1, %2, %0" : "+v"(c) : "v"(a), "v"(b));
  return c;
#endif
}

#define AS1(p) (const __attribute__((address_space(1))) void*)(p)
#define AS3(p) (__attribute__((address_space(3))) void*)(p)

// ---------------- merged f32 -> bf16 convert (5 segments) ----------------
__device__ __forceinline__ void cvt8(const float* __restrict__ in,
                                     unsigned short* __restrict__ out,
                                     int i, float scale) {
  const float4* p = (const float4*)in + (size_t)i * 2;
  float4 a = p[0], b = p[1];
  u16x8 r;
  r[0] = f2b(a.x * scale); r[1] = f2b(a.y * scale);
  r[2] = f2b(a.z * scale); r[3] = f2b(a.w * scale);
  r[4] = f2b(b.x * scale); r[5] = f2b(b.y * scale);
  r[6] = f2b(b.z * scale); r[7] = f2b(b.w * scale);
  *((u16x8*)out + i) = r;
}

__global__ __launch_bounds__(256) void k_cvt_all(
    const float* __restrict__ x,  const float* __restrict__ Wq,
    const float* __restrict__ Wk, const float* __restrict__ Wv,
    const float* __restrict__ Wo, unsigned short* __restrict__ xb,
    unsigned short* __restrict__ wqkv, unsigned short* __restrict__ Wob,
    float sc) {
  int bid = blockIdx.x;                      // 9216 blocks total, 2048 elems each
  int tid = threadIdx.x;
  if (bid < 4096)      cvt8(x,  xb,             (bid        ) * 256 + tid, 1.f);
  else if (bid < 6144) cvt8(Wq, wqkv,           (bid - 4096) * 256 + tid, sc);
  else if (bid < 6656) cvt8(Wk, wqkv + 4194304, (bid - 6144) * 256 + tid, 1.f);
  else if (bid < 7168) cvt8(Wv, wqkv + 5242880, (bid - 6656) * 256 + tid, 1.f);
  else                 cvt8(Wo, Wob,            (bid - 7168) * 256 + tid, 1.f);
}

// ---------------- merged RoPE (q/k cols) + V transpose ----------------
__global__ __launch_bounds__(256) void k_post(unsigned short* __restrict__ qkv,
                                              const float* __restrict__ cosb,
                                              const float* __restrict__ sinb,
                                              unsigned short* __restrict__ vT) {
  __shared__ unsigned short tile[64][72];
  const int bid = blockIdx.x, t = threadIdx.x;
  if (bid < 2560) {
    int tid = bid * 256 + t;                 // 4096*20*8 = 655360
    int oct = tid & 7;
    int hd  = (tid >> 3) % 20;
    int s   = (tid >> 3) / 20;
    unsigned short* p1 = qkv + (size_t)s * 3072 + hd * 128 + oct * 8;
    unsigned short* p2 = p1 + 64;
    u16x8 a = *(const u16x8*)p1;
    u16x8 b = *(const u16x8*)p2;
    const float4* cp = (const float4*)(cosb + (size_t)s * 128 + oct * 8);
    const float4* sp = (const float4*)(sinb + (size_t)s * 128 + oct * 8);
    float4 c0 = cp[0], c1 = cp[1], s0 = sp[0], s1 = sp[1];
    float cs[8] = {c0.x,c0.y,c0.z,c0.w,c1.x,c1.y,c1.z,c1.w};
    float sn[8] = {s0.x,s0.y,s0.z,s0.w,s1.x,s1.y,s1.z,s1.w};
    u16x8 ra, rb;
#pragma unroll
    for (int j = 0; j < 8; ++j) {
      float av = b2f(a[j]), bv = b2f(b[j]);
      ra[j] = f2b(av * cs[j] - bv * sn[j]);
      rb[j] = f2b(bv * cs[j] + av * sn[j]);
    }
    *(u16x8*)p1 = ra;
    *(u16x8*)p2 = rb;
  } else {
    int idx = bid - 2560;                    // 512 tiles
    int bs = idx >> 3, bc = idx & 7;
#pragma unroll
    for (int i = 0; i < 2; ++i) {
      int c8 = t + 256 * i;                  // 0..511
      int row = c8 >> 3, cb = c8 & 7;
      u16x8 v = *(const u16x8*)(qkv + (size_t)(bs * 64 + row) * 3072 + 2560 + bc * 64 + cb * 8);
#pragma unroll
      for (int j = 0; j < 8; ++j) tile[row][cb * 8 + j] = v[j];
    }
    __syncthreads();
#pragma unroll
    for (int i = 0; i < 2; ++i) {
      int c8 = t + 256 * i;
      int crow = c8 >> 3, sb = c8 & 7;
      u16x8 v;
#pragma unroll
      for (int j = 0; j < 8; ++j) v[j] = tile[sb * 8 + j][crow];
      *(u16x8*)(vT + (size_t)(bc * 64 + crow) * 4096 + bs * 64 + sb * 8) = v;
    }
  }
}

// ---------------- 256x256 2-phase GEMM with counted vmcnt (qkv proj) -------
// C[M,N] = A[M,K] @ B[N,K]^T, bf16 in / bf16 out. 8 waves (2x4), BK=64,
// double-buffered 128KB LDS. Per K-tile: phase0 stages A(t+1), waits
// vmcnt(4) (counted: only the 4 just-issued loads stay in flight; tile t's
// 8 loads proven landed), barrier, computes i-half 0; phase1 stages B(t+1),
// computes i-half 1, barrier. No full vmcnt(0) drain inside the loop (T4).
__global__ __launch_bounds__(512, 1) void k_gemm256(
    const unsigned short* __restrict__ A, const unsigned short* __restrict__ B,
    unsigned short* __restrict__ C, int K, int lda, int ldb, int ldc) {
  __shared__ unsigned short As[2][256 * 64];
  __shared__ unsigned short Bs[2][256 * 64];
  const int t = threadIdx.x;                 // 0..511
  const int lane = t & 63, w = t >> 6;
  const int wm = w >> 2, wn = w & 3;         // 2 x 4 wave grid
  const int l15 = lane & 15, lq = lane >> 4;
  const int bn = blockIdx.x, bm = blockIdx.y;
  const unsigned short* Arow = A + (size_t)(bm * 256) * lda;
  const unsigned short* Brow = B + (size_t)(bn * 256) * ldb;
  const int NT = K >> 6;

  // staging round q (0..7): q<4 -> A rows, q>=4 -> B rows. Linear LDS dest,
  // pre-swizzled global source column-chunk (involution with read XOR).
  auto stage = [&](int buf, int kt, int q0, int q1) {
#pragma unroll
    for (int q = q0; q < q1; ++q) {
      int idx = (q & 3) * 512 + t;           // 0..2047
      int r = idx >> 3, blk = idx & 7;
      int sb = blk ^ (r & 7);
      const unsigned short* src =
          (q < 4 ? Arow + (size_t)r * lda : Brow + (size_t)r * ldb) + kt + sb * 8;
      unsigned short* dst = (q < 4 ? As[buf] : Bs[buf]) + (size_t)idx * 8;
      __builtin_amdgcn_global_load_lds(AS1(src), AS3(dst), 16, 0, 0);
    }
  };

  f32x4 acc[8][4] = {};
  stage(0, 0, 0, 8);                         // prologue: tile 0 (A+B)

  for (int tau = 0; tau < NT; ++tau) {
    const int buf = tau & 1;
    const char* Ab = (const char*)As[buf];
    const char* Bb = (const char*)Bs[buf];
    const bool pre = (tau + 1 < NT);
    // ---- phase 0: stage A(t+1); counted wait; B-frags; i-half 0 ----
    if (pre) stage(buf ^ 1, (tau + 1) << 6, 0, 4);
    if (pre) asm volatile("s_waitcnt vmcnt(4)" ::: "memory");
    else     asm volatile("s_waitcnt vmcnt(0)" ::: "memory");
    __builtin_amdgcn_s_barrier();

    bf16x8 bv[4][2];                         // wave's B fragments, held per tile
#pragma unroll
    for (int j = 0; j < 4; ++j)
#pragma unroll
      for (int kk = 0; kk < 2; ++kk) {
        int r = wn * 64 + j * 16 + l15;
        int off = (r * 128 + (kk * 32 + lq * 8) * 2) ^ ((r & 7) << 4);
        bv[j][kk] = *(const bf16x8*)(Bb + off);
      }
    __builtin_amdgcn_s_setprio(1);
#pragma unroll
    for (int i = 0; i < 4; ++i) {
      bf16x8 av[2];
#pragma unroll
      for (int kk = 0; kk < 2; ++kk) {
        int r = wm * 128 + i * 16 + l15;
        int off = (r * 128 + (kk * 32 + lq * 8) * 2) ^ ((r & 7) << 4);
        av[kk] = *(const bf16x8*)(Ab + off);
      }
#pragma unroll
      for (int kk = 0; kk < 2; ++kk)
#pragma unroll
        for (int j = 0; j < 4; ++j)
          acc[i][j] = __builtin_amdgcn_mfma_f32_16x16x32_bf16(av[kk], bv[j][kk], acc[i][j], 0, 0, 0);
    }
    __builtin_amdgcn_s_setprio(0);

    // ---- phase 1: stage B(t+1); i-half 1 ----
    if (pre) stage(buf ^ 1, (tau + 1) << 6, 4, 8);
    __builtin_amdgcn_s_setprio(1);
#pragma unroll
    for (int i = 4; i < 8; ++i) {
      bf16x8 av[2];
#pragma unroll
      for (int kk = 0; kk < 2; ++kk) {
        int r = wm * 128 + i * 16 + l15;
        int off = (r * 128 + (kk * 32 + lq * 8) * 2) ^ ((r & 7) << 4);
        av[kk] = *(const bf16x8*)(Ab + off);
      }
#pragma unroll
      for (int kk = 0; kk < 2; ++kk)
#pragma unroll
        for (int j = 0; j < 4; ++j)
          acc[i][j] = __builtin_amdgcn_mfma_f32_16x16x32_bf16(av[kk], bv[j][kk], acc[i][j], 0, 0, 0);
    }
    __builtin_amdgcn_s_setprio(0);
    __builtin_amdgcn_s_barrier();            // all reads of buf done before t+2 staging
  }

  // ---- epilogue: C write (m89 layout: col=lane&15, row=(lane>>4)*4+r) ----
#pragma unroll
  for (int i = 0; i < 8; ++i)
#pragma unroll
    for (int j = 0; j < 4; ++j)
#pragma unroll
      for (int r = 0; r < 4; ++r) {
        int m = bm * 256 + wm * 128 + i * 16 + lq * 4 + r;
        int n = bn * 256 + wn * 64 + j * 16 + l15;
        C[(size_t)m * ldc + n] = f2b(acc[i][j][r]);
      }
}

// ---------------- GEMM C[M,N] = A[M,K] @ B[N,K]^T (128² proven; out-proj) --
template <int OUTF32>
__global__ __launch_bounds__(256) void k_gemm_bt(
    const unsigned short* __restrict__ A, const unsigned short* __restrict__ B,
    void* __restrict__ C, int K, int lda, int ldb, int ldc) {
  __shared__ unsigned short As[128 * 64];
  __shared__ unsigned short Bs[128 * 64];
  const int t = threadIdx.x;
  const int lane = t & 63, w = t >> 6;
  const int wm = w >> 1, wn = w & 1;
  const int bn = blockIdx.x, bm = blockIdx.y;
  const unsigned short* Arow = A + (size_t)(bm * 128) * lda;
  const unsigned short* Brow = B + (size_t)(bn * 128) * ldb;

  f32x4 acc[4][4] = {};
  for (int kt = 0; kt < K; kt += 64) {
#pragma unroll
    for (int i = 0; i < 4; ++i) {
      int idx = i * 256 + t;
      int r = idx >> 3, blk = idx & 7;
      int sb = blk ^ (r & 7);
      __builtin_amdgcn_global_load_lds(AS1(Arow + (size_t)r * lda + kt + sb * 8),
                                       AS3(As + (i * 256 + w * 64) * 8), 16, 0, 0);
    }
#pragma unroll
    for (int i = 0; i < 4; ++i) {
      int idx = i * 256 + t;
      int r = idx >> 3, blk = idx & 7;
      int sb = blk ^ (r & 7);
      __builtin_amdgcn_global_load_lds(AS1(Brow + (size_t)r * ldb + kt + sb * 8),
                                       AS3(Bs + (i * 256 + w * 64) * 8), 16, 0, 0);
    }
    __syncthreads();
#pragma unroll
    for (int kk = 0; kk < 2; ++kk) {
      bf16x8 av[4], bv[4];
#pragma unroll
      for (int i = 0; i < 4; ++i) {
        int r = wm * 64 + i * 16 + (lane & 15);
        int off = (r * 128 + (kk * 32 + (lane >> 4) * 8) * 2) ^ ((r & 7) << 4);
        av[i] = *(const bf16x8*)((const char*)As + off);
      }
#pragma unroll
      for (int j2 = 0; j2 < 4; ++j2) {
        int r = wn * 64 + j2 * 16 + (lane & 15);
        int off = (r * 128 + (kk * 32 + (lane >> 4) * 8) * 2) ^ ((r & 7) << 4);
        bv[j2] = *(const bf16x8*)((const char*)Bs + off);
      }
#pragma unroll
      for (int i = 0; i < 4; ++i)
#pragma unroll
        for (int j2 = 0; j2 < 4; ++j2)
          acc[i][j2] = __builtin_amdgcn_mfma_f32_16x16x32_bf16(av[i], bv[j2], acc[i][j2], 0, 0, 0);
    }
    __syncthreads();
  }
#pragma unroll
  for (int i = 0; i < 4; ++i)
#pragma unroll
    for (int j2 = 0; j2 < 4; ++j2)
#pragma unroll
      for (int r = 0; r < 4; ++r) {
        int m = bm * 128 + wm * 64 + i * 16 + (lane >> 4) * 4 + r;
        int n = bn * 128 + wn * 64 + j2 * 16 + (lane & 15);
        float v = acc[i][j2][r];
        if (OUTF32) ((float*)C)[(size_t)m * ldc + n] = v;
        else        ((unsigned short*)C)[(size_t)m * ldc + n] = f2b(v);
      }
}

// ---------------- attention staging helpers (r4/r10-proven) ----------------
__device__ __forceinline__ void stage_k(const unsigned short* __restrict__ qk,
                                        unsigned short* __restrict__ dst,
                                        int kt, int g, int t, int w) {
#pragma unroll
  for (int i = 0; i < 4; ++i) {   // K tile [64 keys][128 d], swz low 3 bits of col16
    int idx = i * 256 + t;
    int r = idx >> 4, blk = idx & 15;
    int sb = (blk & 8) | ((blk ^ r) & 7);
    __builtin_amdgcn_global_load_lds(
        AS1(qk + (size_t)(kt * 64 + r) * 3072 + 2048 + g * 128 + sb * 8),
        AS3(dst + (i * 256 + w * 64) * 8), 16, 0, 0);
  }
}
__device__ __forceinline__ void stage_v(const unsigned short* __restrict__ vT,
                                        unsigned short* __restrict__ dst,
                                        int kt, int g, int t, int w) {
#pragma unroll
  for (int i = 0; i < 4; ++i) {   // V^T tile [128 d][64 keys]
    int idx = i * 256 + t;
    int r = idx >> 3, blk = idx & 7;
    int sb = blk ^ (r & 7);
    __builtin_amdgcn_global_load_lds(
        AS1(vT + (size_t)(g * 128 + r) * 4096 + kt * 64 + sb * 8),
        AS3(dst + (i * 256 + w * 64) * 8), 16, 0, 0);
  }
}

// ---------------- fused causal GQA flash attention (r13, best) ----------------
__global__ __launch_bounds__(512, 1) void k_attn(const unsigned short* __restrict__ qk,
                                                 const unsigned short* __restrict__ vT,
                                                 unsigned short* __restrict__ ctx) {
  __shared__ unsigned short Ks[2][2][64 * 128];   // [group][parity]
  __shared__ unsigned short Vs[2][2][64 * 128];
  const int b = blockIdx.x >> 3;             // 0..31
  const int hp = blockIdx.x & 7;             // head pair: heads 2hp, 2hp+1
  const int h0 = hp * 2, g = hp >> 1;
  const int t = threadIdx.x;                 // 0..511
  const int grp = t >> 8;                    // 0 = keys low half, 1 = high half
  const int tg = t & 255;                    // thread within group
  const int lane = t & 63, w4 = (t >> 6) & 3;
  const int l15 = lane & 15, lq = lane >> 4;

  float* ol = (float*)&Ks[0][0][0];          // 64KB combine scratch (post-loop)
  float* ll = (float*)&Vs[0][0][0];          // lsum scratch (post-loop)

  for (int ph = 0; ph < 2; ++ph) {
    const int qt = ph ? 63 - b : b;
    const int ntot = qt + 1;
    const int m = (ntot + 1) >> 1;           // group A tiles [0,m)
    const int nB = ntot - m;                 // group B tiles [m,ntot), nB <= m
    const int kbase = grp ? m : 0;
    const int ntile = grp ? nB : m;
    const int qg = qt * 64 + w4 * 16 + l15;  // this lane's softmax q-row

    bf16x8 aq0[4], aq1[4];        // Q fragments, both heads
    {
      const unsigned short* qb =
          qk + (size_t)(qt * 64 + w4 * 16 + l15) * 3072 + h0 * 128 + lq * 8;
#pragma unroll
      for (int sl = 0; sl < 4; ++sl) {
        aq0[sl] = *(const bf16x8*)(qb + sl * 32);
        aq1[sl] = *(const bf16x8*)(qb + 128 + sl * 32);
      }
    }
    f32x4 o0[8] = {}, o1[8] = {};
    float lsum0 = 0.f, lsum1 = 0.f;

    unsigned short* K0 = Ks[grp][0];
    unsigned short* K1 = Ks[grp][1];
    unsigned short* V0 = Vs[grp][0];
    unsigned short* V1 = Vs[grp][1];

    if (ntile > 0) {                         // prologue: stage my first tile
      stage_k(qk, K0, kbase, g, tg, w4);
      stage_v(vT, V0, kbase, g, tg, w4);
    }
    asm volatile("s_waitcnt vmcnt(0)" ::: "memory");
    __builtin_amdgcn_s_barrier();

    auto tile = [&](const unsigned short* Kb, const unsigned short* Vb,
                    int kt, bool maskT) {
      f32x4 st0[4] = {}, st1[4] = {};
      __builtin_amdgcn_s_setprio(1);
#pragma unroll
      for (int sl = 0; sl < 4; ++sl)
#pragma unroll
        for (int nt = 0; nt < 4; ++nt) {
          int key = nt * 16 + l15;
          int off = (key * 256 + sl * 64 + lq * 16) ^ ((key & 7) << 4);
          bf16x8 bk = *(const bf16x8*)((const char*)Kb + off);
          st0[nt] = __builtin_amdgcn_mfma_f32_16x16x32_bf16(bk, aq0[sl], st0[nt], 0, 0, 0);
          st1[nt] = __builtin_amdgcn_mfma_f32_16x16x32_bf16(bk, aq1[sl], st1[nt], 0, 0, 0);
        }
      __builtin_amdgcn_s_setprio(0);

      bf16x4 pa0[4], pa1[4];
#pragma unroll
      for (int nt = 0; nt < 4; ++nt)
#pragma unroll
        for (int r = 0; r < 4; ++r) {
          float p0 = __builtin_amdgcn_exp2f(st0[nt][r]);
          float p1 = __builtin_amdgcn_exp2f(st1[nt][r]);
          if (maskT) {
            int key = kt * 64 + nt * 16 + lq * 4 + r;
            if (key > qg) { p0 = 0.f; p1 = 0.f; }
          }
          lsum0 += p0; lsum1 += p1;
          unsigned int u0 = __builtin_bit_cast(unsigned int, p0) + 0x8000u;
          unsigned int u1 = __builtin_bit_cast(unsigned int, p1) + 0x8000u;
          pa0[nt][r] = (short)(u0 >> 16);
          pa1[nt][r] = (short)(u1 >> 16);
        }

      __builtin_amdgcn_s_setprio(1);
#pragma unroll
      for (int nt = 0; nt < 4; ++nt)
#pragma unroll
        for (int dt = 0; dt < 8; ++dt) {
          int d = dt * 16 + l15;
          int off = (d * 128 + nt * 32 + lq * 8) ^ ((d & 7) << 4);
          bf16x4 vv = *(const bf16x4*)((const char*)Vb + off);
          o0[dt] = mfma16x16x16(pa0[nt], vv, o0[dt]);
          o1[dt] = mfma16x16x16(pa1[nt], vv, o1[dt]);
        }
      __builtin_amdgcn_s_setprio(0);
    };

    for (int i = 0; i < m; ++i) {            // both groups run m iterations
      const int cur = i & 1;
      if (i + 1 < ntile) {                   // prefetch my next tile
        stage_k(qk, cur ? K0 : K1, kbase + i + 1, g, tg, w4);
        stage_v(vT, cur ? V0 : V1, kbase + i + 1, g, tg, w4);
      }
      if (i < ntile) {
        const int kt = kbase + i;
        tile(cur ? K1 : K0, cur ? V1 : V0, kt, kt == qt);
      }
      asm volatile("s_waitcnt vmcnt(0)" ::: "memory");
      __builtin_amdgcn_s_barrier();          // also fences K/V reads for reuse
    }

    // ---- combine: O = (O_A + O_B) / (l_A + l_B) via LDS ----
    float f0 = lsum0, f1 = lsum1;            // reduce partial row sums
    f0 += __shfl_xor(f0, 16); f0 += __shfl_xor(f0, 32);
    f1 += __shfl_xor(f1, 16); f1 += __shfl_xor(f1, 32);

    if (grp == 1) {                          // B publishes partials
#pragma unroll
      for (int dt = 0; dt < 8; ++dt)
#pragma unroll
        for (int r = 0; r < 4; ++r) {
          ol[(dt * 4 + r) * 256 + tg]        = o0[dt][r];
          ol[(32 + dt * 4 + r) * 256 + tg]   = o1[dt][r];
        }
      if (lq == 0) {
        ll[w4 * 16 + l15]      = f0;
        ll[64 + w4 * 16 + l15] = f1;
      }
    }
    __builtin_amdgcn_s_barrier();
    if (grp == 0) {                          // A combines, normalizes, stores
#pragma unroll
      for (int dt = 0; dt < 8; ++dt)
#pragma unroll
        for (int r = 0; r < 4; ++r) {
          o0[dt][r] += ol[(dt * 4 + r) * 256 + tg];
          o1[dt][r] += ol[(32 + dt * 4 + r) * 256 + tg];
        }
      f0 += ll[w4 * 16 + l15];
      f1 += ll[64 + w4 * 16 + l15];
      float iq0[4], iq1[4];
#pragma unroll
      for (int r = 0; r < 4; ++r) {
        iq0[r] = 1.f / __shfl(f0, lq * 4 + r);
        iq1[r] = 1.f / __shfl(f1, lq * 4 + r);
      }
#pragma unroll
      for (int dt = 0; dt < 8; ++dt)
#pragma unroll
        for (int r = 0; r < 4; ++r) {
          int q = qt * 64 + w4 * 16 + lq * 4 + r;
          int c = h0 * 128 + dt * 16 + l15;
          ctx[(size_t)q * 2048 + c]       = f2b(o0[dt][r] * iq0[r]);
          ctx[(size_t)q * 2048 + c + 128] = f2b(o1[dt][r] * iq1[r]);
        }
    }
    __builtin_amdgcn_s_barrier();            // protect LDS for next phase
  }
}

// ---------------- host ----------------
extern "C" void kernel_launch(void* const* d_in, const int* in_sizes, int n_in,
                              void* d_out, int out_size, void* d_ws, size_t ws_size,
                              hipStream_t stream) {
  const float* x    = (const float*)d_in[0];
  const float* cosb = (const float*)d_in[2];
  const float* sinb = (const float*)d_in[3];
  const float* Wq   = (const float*)d_in[4];
  const float* Wk   = (const float*)d_in[5];
  const float* Wv   = (const float*)d_in[6];
  const float* Wo   = (const float*)d_in[7];

  char* p = (char*)d_ws;
  unsigned short* xb   = (unsigned short*)p; p += (size_t)8388608 * 2;   // x bf16
  unsigned short* wqkv = (unsigned short*)p; p += (size_t)6291456 * 2;   // [3072][2048]
  unsigned short* Wob  = (unsigned short*)p; p += (size_t)4194304 * 2;
  unsigned short* qkvb = (unsigned short*)p; p += (size_t)4096 * 3072 * 2;
  unsigned short* vTb  = (unsigned short*)p; p += (size_t)512 * 4096 * 2;
  unsigned short* ctx  = (unsigned short*)p; p += (size_t)4096 * 2048 * 2;
  if (ws_size < (size_t)(p - (char*)d_ws)) return;

  const float SC = 0.12751741f;   // (1/sqrt(128)) * log2(e), folded into Wq

  k_cvt_all<<<9216, 256, 0, stream>>>(x, Wq, Wk, Wv, Wo, xb, wqkv, Wob, SC);

  // qkv = x @ [Wq;Wk;Wv]^T  -> [4096][3072] via 256² 2-phase counted-vmcnt GEMM
  k_gemm256<<<dim3(12, 16), 512, 0, stream>>>(xb, wqkv, qkvb, 2048, 2048, 2048, 3072);

  k_post<<<3072, 256, 0, stream>>>(qkvb, cosb, sinb, vTb);

  k_attn<<<256, 512, 0, stream>>>(qkvb, vTb, ctx);

  k_gemm_bt<1><<<dim3(16, 32), 256, 0, stream>>>(ctx, Wob, d_out, 2048, 2048, 2048, 2048);
}

// Round 17
// 225.051 us; speedup vs baseline: 1.0690x; 1.0334x over previous
//
#include <hip/hip_runtime.h>

typedef __attribute__((ext_vector_type(8))) short bf16x8;     // 8 bf16 in 4 VGPRs
typedef __attribute__((ext_vector_type(4))) short bf16x4;     // 4 bf16 in 2 VGPRs
typedef __attribute__((ext_vector_type(8))) unsigned short u16x8;
typedef __attribute__((ext_vector_type(4))) float f32x4;

__device__ __forceinline__ unsigned short f2b(float f) {      // f32 -> bf16 RNE
  unsigned int u = __builtin_bit_cast(unsigned int, f);
  u += 0x7FFFu + ((u >> 16) & 1u);
  return (unsigned short)(u >> 16);
}
__device__ __forceinline__ float b2f(unsigned short h) {
  return __builtin_bit_cast(float, ((unsigned int)h) << 16);
}

__device__ __forceinline__ f32x4 mfma16x16x16(bf16x4 a, bf16x4 b, f32x4 c) {
#if __has_builtin(__builtin_amdgcn_mfma_f32_16x16x16bf16_1k)
  return __builtin_amdgcn_mfma_f32_16x16x16bf16_1k(a, b, c, 0, 0, 0);
#else
  asm volatile("v_mfma_f32_16x16x16_bf16 %0, %1, %2, %0" : "+v"(c) : "v"(a), "v"(b));
  return c;
#endif
}

#define AS1(p) (const __attribute__((address_space(1))) void*)(p)
#define AS3(p) (__attribute__((address_space(3))) void*)(p)

// ---------------- merged f32 -> bf16 convert (5 segments) ----------------
__device__ __forceinline__ void cvt8(const float* __restrict__ in,
                                     unsigned short* __restrict__ out,
                                     int i, float scale) {
  const float4* p = (const float4*)in + (size_t)i * 2;
  float4 a = p[0], b = p[1];
  u16x8 r;
  r[0] = f2b(a.x * scale); r[1] = f2b(a.y * scale);
  r[2] = f2b(a.z * scale); r[3] = f2b(a.w * scale);
  r[4] = f2b(b.x * scale); r[5] = f2b(b.y * scale);
  r[6] = f2b(b.z * scale); r[7] = f2b(b.w * scale);
  *((u16x8*)out + i) = r;
}

__global__ __launch_bounds__(256) void k_cvt_all(
    const float* __restrict__ x,  const float* __restrict__ Wq,
    const float* __restrict__ Wk, const float* __restrict__ Wv,
    const float* __restrict__ Wo, unsigned short* __restrict__ xb,
    unsigned short* __restrict__ wqkv, unsigned short* __restrict__ Wob,
    float sc) {
  int bid = blockIdx.x;                      // 9216 blocks total, 2048 elems each
  int tid = threadIdx.x;
  if (bid < 4096)      cvt8(x,  xb,             (bid        ) * 256 + tid, 1.f);
  else if (bid < 6144) cvt8(Wq, wqkv,           (bid - 4096) * 256 + tid, sc);
  else if (bid < 6656) cvt8(Wk, wqkv + 4194304, (bid - 6144) * 256 + tid, 1.f);
  else if (bid < 7168) cvt8(Wv, wqkv + 5242880, (bid - 6656) * 256 + tid, 1.f);
  else                 cvt8(Wo, Wob,            (bid - 7168) * 256 + tid, 1.f);
}

// ---------------- V transpose only (rope fused into GEMM epilogue) ---------
__global__ __launch_bounds__(256) void k_tr(const unsigned short* __restrict__ qkv,
                                            unsigned short* __restrict__ vT) {
  __shared__ unsigned short tile[64][72];
  const int idx = blockIdx.x, t = threadIdx.x;  // 512 tiles
  const int bs = idx >> 3, bc = idx & 7;
#pragma unroll
  for (int i = 0; i < 2; ++i) {
    int c8 = t + 256 * i;                    // 0..511
    int row = c8 >> 3, cb = c8 & 7;
    u16x8 v = *(const u16x8*)(qkv + (size_t)(bs * 64 + row) * 3072 + 2560 + bc * 64 + cb * 8);
#pragma unroll
    for (int j = 0; j < 8; ++j) tile[row][cb * 8 + j] = v[j];
  }
  __syncthreads();
#pragma unroll
  for (int i = 0; i < 2; ++i) {
    int c8 = t + 256 * i;
    int crow = c8 >> 3, sb = c8 & 7;
    u16x8 v;
#pragma unroll
    for (int j = 0; j < 8; ++j) v[j] = tile[sb * 8 + j][crow];
    *(u16x8*)(vT + (size_t)(bc * 64 + crow) * 4096 + bs * 64 + sb * 8) = v;
  }
}

// ---------------- 256x256 2-phase GEMM, counted vmcnt, FUSED RoPE epilogue --
// C[M,N] = A[M,K] @ B[N,K]^T, bf16 in / bf16 out (qkv projection).
// Main loop unchanged from r16. Epilogue: for q/k column-blocks (bn<10),
// rope pairs (d, d+64) live in adjacent waves (wn^1, same lane/i/j/r) ->
// 2-round LDS exchange through the (now dead) 128KB staging LDS, rope on
// unrounded f32 acc, single store. v-blocks (bn>=10) plain-store.
__global__ __launch_bounds__(512, 1) void k_gemm256(
    const unsigned short* __restrict__ A, const unsigned short* __restrict__ B,
    unsigned short* __restrict__ C, const float* __restrict__ cosb,
    const float* __restrict__ sinb, int K, int lda, int ldb, int ldc) {
  __shared__ unsigned short LDS[2][2][256 * 64];   // [buf][A/B] 128KB total
  const int t = threadIdx.x;                 // 0..511
  const int lane = t & 63, w = t >> 6;
  const int wm = w >> 2, wn = w & 3;         // 2 x 4 wave grid
  const int l15 = lane & 15, lq = lane >> 4;
  const int bn = blockIdx.x, bm = blockIdx.y;
  const unsigned short* Arow = A + (size_t)(bm * 256) * lda;
  const unsigned short* Brow = B + (size_t)(bn * 256) * ldb;
  const int NT = K >> 6;

  auto stage = [&](int buf, int kt, int q0, int q1) {
#pragma unroll
    for (int q = q0; q < q1; ++q) {
      int idx = (q & 3) * 512 + t;           // 0..2047
      int r = idx >> 3, blk = idx & 7;
      int sb = blk ^ (r & 7);
      const unsigned short* src =
          (q < 4 ? Arow + (size_t)r * lda : Brow + (size_t)r * ldb) + kt + sb * 8;
      unsigned short* dst = (q < 4 ? &LDS[buf][0][0] : &LDS[buf][1][0]) + (size_t)idx * 8;
      __builtin_amdgcn_global_load_lds(AS1(src), AS3(dst), 16, 0, 0);
    }
  };

  f32x4 acc[8][4] = {};
  stage(0, 0, 0, 8);                         // prologue: tile 0 (A+B)

  for (int tau = 0; tau < NT; ++tau) {
    const int buf = tau & 1;
    const char* Ab = (const char*)&LDS[buf][0][0];
    const char* Bb = (const char*)&LDS[buf][1][0];
    const bool pre = (tau + 1 < NT);
    // ---- phase 0: stage A(t+1); counted wait; B-frags; i-half 0 ----
    if (pre) stage(buf ^ 1, (tau + 1) << 6, 0, 4);
    if (pre) asm volatile("s_waitcnt vmcnt(4)" ::: "memory");
    else     asm volatile("s_waitcnt vmcnt(0)" ::: "memory");
    __builtin_amdgcn_s_barrier();

    bf16x8 bv[4][2];                         // wave's B fragments, held per tile
#pragma unroll
    for (int j = 0; j < 4; ++j)
#pragma unroll
      for (int kk = 0; kk < 2; ++kk) {
        int r = wn * 64 + j * 16 + l15;
        int off = (r * 128 + (kk * 32 + lq * 8) * 2) ^ ((r & 7) << 4);
        bv[j][kk] = *(const bf16x8*)(Bb + off);
      }
    __builtin_amdgcn_s_setprio(1);
#pragma unroll
    for (int i = 0; i < 4; ++i) {
      bf16x8 av[2];
#pragma unroll
      for (int kk = 0; kk < 2; ++kk) {
        int r = wm * 128 + i * 16 + l15;
        int off = (r * 128 + (kk * 32 + lq * 8) * 2) ^ ((r & 7) << 4);
        av[kk] = *(const bf16x8*)(Ab + off);
      }
#pragma unroll
      for (int kk = 0; kk < 2; ++kk)
#pragma unroll
        for (int j = 0; j < 4; ++j)
          acc[i][j] = __builtin_amdgcn_mfma_f32_16x16x32_bf16(av[kk], bv[j][kk], acc[i][j], 0, 0, 0);
    }
    __builtin_amdgcn_s_setprio(0);

    // ---- phase 1: stage B(t+1); i-half 1 ----
    if (pre) stage(buf ^ 1, (tau + 1) << 6, 4, 8);
    __builtin_amdgcn_s_setprio(1);
#pragma unroll
    for (int i = 4; i < 8; ++i) {
      bf16x8 av[2];
#pragma unroll
      for (int kk = 0; kk < 2; ++kk) {
        int r = wm * 128 + i * 16 + l15;
        int off = (r * 128 + (kk * 32 + lq * 8) * 2) ^ ((r & 7) << 4);
        av[kk] = *(const bf16x8*)(Ab + off);
      }
#pragma unroll
      for (int kk = 0; kk < 2; ++kk)
#pragma unroll
        for (int j = 0; j < 4; ++j)
          acc[i][j] = __builtin_amdgcn_mfma_f32_16x16x32_bf16(av[kk], bv[j][kk], acc[i][j], 0, 0, 0);
    }
    __builtin_amdgcn_s_setprio(0);
    __builtin_amdgcn_s_barrier();            // all reads of buf done before t+2 staging
  }

  // ---- epilogue ----
  if (bn < 10) {
    // q/k columns: fused RoPE. Partner (col^64) is wave wn^1, same lane/i/j/r.
    float* ex = (float*)&LDS[0][0][0];       // 128KB scratch (staging dead)
    const float sgn = (wn & 1) ? 1.f : -1.f; // upper half: +sin, lower: -sin
#pragma unroll
    for (int h = 0; h < 2; ++h) {            // 2 rounds over i-halves
      __builtin_amdgcn_s_barrier();          // prior round reads / K-loop done
#pragma unroll
      for (int i2 = 0; i2 < 4; ++i2)
#pragma unroll
        for (int j = 0; j < 4; ++j)
          *(f32x4*)&ex[(((w * 4 + i2) * 4 + j) << 8) + (lane << 2)] = acc[h * 4 + i2][j];
      __builtin_amdgcn_s_barrier();
#pragma unroll
      for (int i2 = 0; i2 < 4; ++i2) {
        int i = h * 4 + i2;
#pragma unroll
        for (int j = 0; j < 4; ++j) {
          f32x4 pv = *(const f32x4*)&ex[((((w ^ 1) * 4 + i2) * 4 + j) << 8) + (lane << 2)];
          int d0 = j * 16 + l15;             // own index mod 64 (tables duplicate)
          int n = bn * 256 + wn * 64 + j * 16 + l15;
#pragma unroll
          for (int r = 0; r < 4; ++r) {
            int m = bm * 256 + wm * 128 + i * 16 + lq * 4 + r;
            float cs = cosb[(size_t)m * 128 + d0];
            float sn = sinb[(size_t)m * 128 + d0];
            float v = acc[i][j][r] * cs + sgn * pv[r] * sn;
            C[(size_t)m * ldc + n] = f2b(v);
          }
        }
      }
    }
  } else {
    // v columns: plain store
#pragma unroll
    for (int i = 0; i < 8; ++i)
#pragma unroll
      for (int j = 0; j < 4; ++j)
#pragma unroll
        for (int r = 0; r < 4; ++r) {
          int m = bm * 256 + wm * 128 + i * 16 + lq * 4 + r;
          int n = bn * 256 + wn * 64 + j * 16 + l15;
          C[(size_t)m * ldc + n] = f2b(acc[i][j][r]);
        }
  }
}

// ---------------- GEMM C[M,N] = A[M,K] @ B[N,K]^T (128² proven; out-proj) --
template <int OUTF32>
__global__ __launch_bounds__(256) void k_gemm_bt(
    const unsigned short* __restrict__ A, const unsigned short* __restrict__ B,
    void* __restrict__ C, int K, int lda, int ldb, int ldc) {
  __shared__ unsigned short As[128 * 64];
  __shared__ unsigned short Bs[128 * 64];
  const int t = threadIdx.x;
  const int lane = t & 63, w = t >> 6;
  const int wm = w >> 1, wn = w & 1;
  const int bn = blockIdx.x, bm = blockIdx.y;
  const unsigned short* Arow = A + (size_t)(bm * 128) * lda;
  const unsigned short* Brow = B + (size_t)(bn * 128) * ldb;

  f32x4 acc[4][4] = {};
  for (int kt = 0; kt < K; kt += 64) {
#pragma unroll
    for (int i = 0; i < 4; ++i) {
      int idx = i * 256 + t;
      int r = idx >> 3, blk = idx & 7;
      int sb = blk ^ (r & 7);
      __builtin_amdgcn_global_load_lds(AS1(Arow + (size_t)r * lda + kt + sb * 8),
                                       AS3(As + (i * 256 + w * 64) * 8), 16, 0, 0);
    }
#pragma unroll
    for (int i = 0; i < 4; ++i) {
      int idx = i * 256 + t;
      int r = idx >> 3, blk = idx & 7;
      int sb = blk ^ (r & 7);
      __builtin_amdgcn_global_load_lds(AS1(Brow + (size_t)r * ldb + kt + sb * 8),
                                       AS3(Bs + (i * 256 + w * 64) * 8), 16, 0, 0);
    }
    __syncthreads();
#pragma unroll
    for (int kk = 0; kk < 2; ++kk) {
      bf16x8 av[4], bv[4];
#pragma unroll
      for (int i = 0; i < 4; ++i) {
        int r = wm * 64 + i * 16 + (lane & 15);
        int off = (r * 128 + (kk * 32 + (lane >> 4) * 8) * 2) ^ ((r & 7) << 4);
        av[i] = *(const bf16x8*)((const char*)As + off);
      }
#pragma unroll
      for (int j2 = 0; j2 < 4; ++j2) {
        int r = wn * 64 + j2 * 16 + (lane & 15);
        int off = (r * 128 + (kk * 32 + (lane >> 4) * 8) * 2) ^ ((r & 7) << 4);
        bv[j2] = *(const bf16x8*)((const char*)Bs + off);
      }
#pragma unroll
      for (int i = 0; i < 4; ++i)
#pragma unroll
        for (int j2 = 0; j2 < 4; ++j2)
          acc[i][j2] = __builtin_amdgcn_mfma_f32_16x16x32_bf16(av[i], bv[j2], acc[i][j2], 0, 0, 0);
    }
    __syncthreads();
  }
#pragma unroll
  for (int i = 0; i < 4; ++i)
#pragma unroll
    for (int j2 = 0; j2 < 4; ++j2)
#pragma unroll
      for (int r = 0; r < 4; ++r) {
        int m = bm * 128 + wm * 64 + i * 16 + (lane >> 4) * 4 + r;
        int n = bn * 128 + wn * 64 + j2 * 16 + (lane & 15);
        float v = acc[i][j2][r];
        if (OUTF32) ((float*)C)[(size_t)m * ldc + n] = v;
        else        ((unsigned short*)C)[(size_t)m * ldc + n] = f2b(v);
      }
}

// ---------------- attention staging helpers (r4/r10-proven) ----------------
__device__ __forceinline__ void stage_k(const unsigned short* __restrict__ qk,
                                        unsigned short* __restrict__ dst,
                                        int kt, int g, int t, int w) {
#pragma unroll
  for (int i = 0; i < 4; ++i) {   // K tile [64 keys][128 d], swz low 3 bits of col16
    int idx = i * 256 + t;
    int r = idx >> 4, blk = idx & 15;
    int sb = (blk & 8) | ((blk ^ r) & 7);
    __builtin_amdgcn_global_load_lds(
        AS1(qk + (size_t)(kt * 64 + r) * 3072 + 2048 + g * 128 + sb * 8),
        AS3(dst + (i * 256 + w * 64) * 8), 16, 0, 0);
  }
}
__device__ __forceinline__ void stage_v(const unsigned short* __restrict__ vT,
                                        unsigned short* __restrict__ dst,
                                        int kt, int g, int t, int w) {
#pragma unroll
  for (int i = 0; i < 4; ++i) {   // V^T tile [128 d][64 keys]
    int idx = i * 256 + t;
    int r = idx >> 3, blk = idx & 7;
    int sb = blk ^ (r & 7);
    __builtin_amdgcn_global_load_lds(
        AS1(vT + (size_t)(g * 128 + r) * 4096 + kt * 64 + sb * 8),
        AS3(dst + (i * 256 + w * 64) * 8), 16, 0, 0);
  }
}

// ---------------- fused causal GQA flash attention (r13, best) ----------------
__global__ __launch_bounds__(512, 1) void k_attn(const unsigned short* __restrict__ qk,
                                                 const unsigned short* __restrict__ vT,
                                                 unsigned short* __restrict__ ctx) {
  __shared__ unsigned short Ks[2][2][64 * 128];   // [group][parity]
  __shared__ unsigned short Vs[2][2][64 * 128];
  const int b = blockIdx.x >> 3;             // 0..31
  const int hp = blockIdx.x & 7;             // head pair: heads 2hp, 2hp+1
  const int h0 = hp * 2, g = hp >> 1;
  const int t = threadIdx.x;                 // 0..511
  const int grp = t >> 8;                    // 0 = keys low half, 1 = high half
  const int tg = t & 255;                    // thread within group
  const int lane = t & 63, w4 = (t >> 6) & 3;
  const int l15 = lane & 15, lq = lane >> 4;

  float* ol = (float*)&Ks[0][0][0];          // 64KB combine scratch (post-loop)
  float* ll = (float*)&Vs[0][0][0];          // lsum scratch (post-loop)

  for (int ph = 0; ph < 2; ++ph) {
    const int qt = ph ? 63 - b : b;
    const int ntot = qt + 1;
    const int m = (ntot + 1) >> 1;           // group A tiles [0,m)
    const int nB = ntot - m;                 // group B tiles [m,ntot), nB <= m
    const int kbase = grp ? m : 0;
    const int ntile = grp ? nB : m;
    const int qg = qt * 64 + w4 * 16 + l15;  // this lane's softmax q-row

    bf16x8 aq0[4], aq1[4];        // Q fragments, both heads
    {
      const unsigned short* qb =
          qk + (size_t)(qt * 64 + w4 * 16 + l15) * 3072 + h0 * 128 + lq * 8;
#pragma unroll
      for (int sl = 0; sl < 4; ++sl) {
        aq0[sl] = *(const bf16x8*)(qb + sl * 32);
        aq1[sl] = *(const bf16x8*)(qb + 128 + sl * 32);
      }
    }
    f32x4 o0[8] = {}, o1[8] = {};
    float lsum0 = 0.f, lsum1 = 0.f;

    unsigned short* K0 = Ks[grp][0];
    unsigned short* K1 = Ks[grp][1];
    unsigned short* V0 = Vs[grp][0];
    unsigned short* V1 = Vs[grp][1];

    if (ntile > 0) {                         // prologue: stage my first tile
      stage_k(qk, K0, kbase, g, tg, w4);
      stage_v(vT, V0, kbase, g, tg, w4);
    }
    asm volatile("s_waitcnt vmcnt(0)" ::: "memory");
    __builtin_amdgcn_s_barrier();

    auto tile = [&](const unsigned short* Kb, const unsigned short* Vb,
                    int kt, bool maskT) {
      f32x4 st0[4] = {}, st1[4] = {};
      __builtin_amdgcn_s_setprio(1);
#pragma unroll
      for (int sl = 0; sl < 4; ++sl)
#pragma unroll
        for (int nt = 0; nt < 4; ++nt) {
          int key = nt * 16 + l15;
          int off = (key * 256 + sl * 64 + lq * 16) ^ ((key & 7) << 4);
          bf16x8 bk = *(const bf16x8*)((const char*)Kb + off);
          st0[nt] = __builtin_amdgcn_mfma_f32_16x16x32_bf16(bk, aq0[sl], st0[nt], 0, 0, 0);
          st1[nt] = __builtin_amdgcn_mfma_f32_16x16x32_bf16(bk, aq1[sl], st1[nt], 0, 0, 0);
        }
      __builtin_amdgcn_s_setprio(0);

      bf16x4 pa0[4], pa1[4];
#pragma unroll
      for (int nt = 0; nt < 4; ++nt)
#pragma unroll
        for (int r = 0; r < 4; ++r) {
          float p0 = __builtin_amdgcn_exp2f(st0[nt][r]);
          float p1 = __builtin_amdgcn_exp2f(st1[nt][r]);
          if (maskT) {
            int key = kt * 64 + nt * 16 + lq * 4 + r;
            if (key > qg) { p0 = 0.f; p1 = 0.f; }
          }
          lsum0 += p0; lsum1 += p1;
          unsigned int u0 = __builtin_bit_cast(unsigned int, p0) + 0x8000u;
          unsigned int u1 = __builtin_bit_cast(unsigned int, p1) + 0x8000u;
          pa0[nt][r] = (short)(u0 >> 16);
          pa1[nt][r] = (short)(u1 >> 16);
        }

      __builtin_amdgcn_s_setprio(1);
#pragma unroll
      for (int nt = 0; nt < 4; ++nt)
#pragma unroll
        for (int dt = 0; dt < 8; ++dt) {
          int d = dt * 16 + l15;
          int off = (d * 128 + nt * 32 + lq * 8) ^ ((d & 7) << 4);
          bf16x4 vv = *(const bf16x4*)((const char*)Vb + off);
          o0[dt] = mfma16x16x16(pa0[nt], vv, o0[dt]);
          o1[dt] = mfma16x16x16(pa1[nt], vv, o1[dt]);
        }
      __builtin_amdgcn_s_setprio(0);
    };

    for (int i = 0; i < m; ++i) {            // both groups run m iterations
      const int cur = i & 1;
      if (i + 1 < ntile) {                   // prefetch my next tile
        stage_k(qk, cur ? K0 : K1, kbase + i + 1, g, tg, w4);
        stage_v(vT, cur ? V0 : V1, kbase + i + 1, g, tg, w4);
      }
      if (i < ntile) {
        const int kt = kbase + i;
        tile(cur ? K1 : K0, cur ? V1 : V0, kt, kt == qt);
      }
      asm volatile("s_waitcnt vmcnt(0)" ::: "memory");
      __builtin_amdgcn_s_barrier();          // also fences K/V reads for reuse
    }

    // ---- combine: O = (O_A + O_B) / (l_A + l_B) via LDS ----
    float f0 = lsum0, f1 = lsum1;            // reduce partial row sums
    f0 += __shfl_xor(f0, 16); f0 += __shfl_xor(f0, 32);
    f1 += __shfl_xor(f1, 16); f1 += __shfl_xor(f1, 32);

    if (grp == 1) {                          // B publishes partials
#pragma unroll
      for (int dt = 0; dt < 8; ++dt)
#pragma unroll
        for (int r = 0; r < 4; ++r) {
          ol[(dt * 4 + r) * 256 + tg]        = o0[dt][r];
          ol[(32 + dt * 4 + r) * 256 + tg]   = o1[dt][r];
        }
      if (lq == 0) {
        ll[w4 * 16 + l15]      = f0;
        ll[64 + w4 * 16 + l15] = f1;
      }
    }
    __builtin_amdgcn_s_barrier();
    if (grp == 0) {                          // A combines, normalizes, stores
#pragma unroll
      for (int dt = 0; dt < 8; ++dt)
#pragma unroll
        for (int r = 0; r < 4; ++r) {
          o0[dt][r] += ol[(dt * 4 + r) * 256 + tg];
          o1[dt][r] += ol[(32 + dt * 4 + r) * 256 + tg];
        }
      f0 += ll[w4 * 16 + l15];
      f1 += ll[64 + w4 * 16 + l15];
      float iq0[4], iq1[4];
#pragma unroll
      for (int r = 0; r < 4; ++r) {
        iq0[r] = 1.f / __shfl(f0, lq * 4 + r);
        iq1[r] = 1.f / __shfl(f1, lq * 4 + r);
      }
#pragma unroll
      for (int dt = 0; dt < 8; ++dt)
#pragma unroll
        for (int r = 0; r < 4; ++r) {
          int q = qt * 64 + w4 * 16 + lq * 4 + r;
          int c = h0 * 128 + dt * 16 + l15;
          ctx[(size_t)q * 2048 + c]       = f2b(o0[dt][r] * iq0[r]);
          ctx[(size_t)q * 2048 + c + 128] = f2b(o1[dt][r] * iq1[r]);
        }
    }
    __builtin_amdgcn_s_barrier();            // protect LDS for next phase
  }
}

// ---------------- host ----------------
extern "C" void kernel_launch(void* const* d_in, const int* in_sizes, int n_in,
                              void* d_out, int out_size, void* d_ws, size_t ws_size,
                              hipStream_t stream) {
  const float* x    = (const float*)d_in[0];
  const float* cosb = (const float*)d_in[2];
  const float* sinb = (const float*)d_in[3];
  const float* Wq   = (const float*)d_in[4];
  const float* Wk   = (const float*)d_in[5];
  const float* Wv   = (const float*)d_in[6];
  const float* Wo   = (const float*)d_in[7];

  char* p = (char*)d_ws;
  unsigned short* xb   = (unsigned short*)p; p += (size_t)8388608 * 2;   // x bf16
  unsigned short* wqkv = (unsigned short*)p; p += (size_t)6291456 * 2;   // [3072][2048]
  unsigned short* Wob  = (unsigned short*)p; p += (size_t)4194304 * 2;
  unsigned short* qkvb = (unsigned short*)p; p += (size_t)4096 * 3072 * 2;
  unsigned short* vTb  = (unsigned short*)p; p += (size_t)512 * 4096 * 2;
  unsigned short* ctx  = (unsigned short*)p; p += (size_t)4096 * 2048 * 2;
  if (ws_size < (size_t)(p - (char*)d_ws)) return;

  const float SC = 0.12751741f;   // (1/sqrt(128)) * log2(e), folded into Wq

  k_cvt_all<<<9216, 256, 0, stream>>>(x, Wq, Wk, Wv, Wo, xb, wqkv, Wob, SC);

  // qkv = x @ [Wq;Wk;Wv]^T -> [4096][3072], RoPE fused in epilogue (q/k cols)
  k_gemm256<<<dim3(12, 16), 512, 0, stream>>>(xb, wqkv, qkvb, cosb, sinb,
                                              2048, 2048, 2048, 3072);

  k_tr<<<512, 256, 0, stream>>>(qkvb, vTb);

  k_attn<<<256, 512, 0, stream>>>(qkvb, vTb, ctx);

  k_gemm_bt<1><<<dim3(16, 32), 256, 0, stream>>>(ctx, Wob, d_out, 2048, 2048, 2048, 2048);
}

// Round 18
// 224.991 us; speedup vs baseline: 1.0692x; 1.0003x over previous
//
#include <hip/hip_runtime.h>

typedef __attribute__((ext_vector_type(8))) short bf16x8;     // 8 bf16 in 4 VGPRs
typedef __attribute__((ext_vector_type(4))) short bf16x4;     // 4 bf16 in 2 VGPRs
typedef __attribute__((ext_vector_type(8))) unsigned short u16x8;
typedef __attribute__((ext_vector_type(4))) float f32x4;

__device__ __forceinline__ unsigned short f2b(float f) {      // f32 -> bf16 RNE
  unsigned int u = __builtin_bit_cast(unsigned int, f);
  u += 0x7FFFu + ((u >> 16) & 1u);
  return (unsigned short)(u >> 16);
}
__device__ __forceinline__ float b2f(unsigned short h) {
  return __builtin_bit_cast(float, ((unsigned int)h) << 16);
}

__device__ __forceinline__ f32x4 mfma16x16x16(bf16x4 a, bf16x4 b, f32x4 c) {
#if __has_builtin(__builtin_amdgcn_mfma_f32_16x16x16bf16_1k)
  return __builtin_amdgcn_mfma_f32_16x16x16bf16_1k(a, b, c, 0, 0, 0);
#else
  asm volatile("v_mfma_f32_16x16x16_bf16 %0, %1, %2, %0" : "+v"(c) : "v"(a), "v"(b));
  return c;
#endif
}

#define AS1(p) (const __attribute__((address_space(1))) void*)(p)
#define AS3(p) (__attribute__((address_space(3))) void*)(p)

// ---------------- merged f32 -> bf16 convert (5 segments) ----------------
__device__ __forceinline__ void cvt8(const float* __restrict__ in,
                                     unsigned short* __restrict__ out,
                                     int i, float scale) {
  const float4* p = (const float4*)in + (size_t)i * 2;
  float4 a = p[0], b = p[1];
  u16x8 r;
  r[0] = f2b(a.x * scale); r[1] = f2b(a.y * scale);
  r[2] = f2b(a.z * scale); r[3] = f2b(a.w * scale);
  r[4] = f2b(b.x * scale); r[5] = f2b(b.y * scale);
  r[6] = f2b(b.z * scale); r[7] = f2b(b.w * scale);
  *((u16x8*)out + i) = r;
}

__global__ __launch_bounds__(256) void k_cvt_all(
    const float* __restrict__ x,  const float* __restrict__ Wq,
    const float* __restrict__ Wk, const float* __restrict__ Wv,
    const float* __restrict__ Wo, unsigned short* __restrict__ xb,
    unsigned short* __restrict__ wqkv, unsigned short* __restrict__ Wob,
    float sc) {
  int bid = blockIdx.x;                      // 9216 blocks total, 2048 elems each
  int tid = threadIdx.x;
  if (bid < 4096)      cvt8(x,  xb,             (bid        ) * 256 + tid, 1.f);
  else if (bid < 6144) cvt8(Wq, wqkv,           (bid - 4096) * 256 + tid, sc);
  else if (bid < 6656) cvt8(Wk, wqkv + 4194304, (bid - 6144) * 256 + tid, 1.f);
  else if (bid < 7168) cvt8(Wv, wqkv + 5242880, (bid - 6656) * 256 + tid, 1.f);
  else                 cvt8(Wo, Wob,            (bid - 7168) * 256 + tid, 1.f);
}

// ---------------- V transpose only (rope fused into GEMM epilogue) ---------
__global__ __launch_bounds__(256) void k_tr(const unsigned short* __restrict__ qkv,
                                            unsigned short* __restrict__ vT) {
  __shared__ unsigned short tile[64][72];
  const int idx = blockIdx.x, t = threadIdx.x;  // 512 tiles
  const int bs = idx >> 3, bc = idx & 7;
#pragma unroll
  for (int i = 0; i < 2; ++i) {
    int c8 = t + 256 * i;                    // 0..511
    int row = c8 >> 3, cb = c8 & 7;
    u16x8 v = *(const u16x8*)(qkv + (size_t)(bs * 64 + row) * 3072 + 2560 + bc * 64 + cb * 8);
#pragma unroll
    for (int j = 0; j < 8; ++j) tile[row][cb * 8 + j] = v[j];
  }
  __syncthreads();
#pragma unroll
  for (int i = 0; i < 2; ++i) {
    int c8 = t + 256 * i;
    int crow = c8 >> 3, sb = c8 & 7;
    u16x8 v;
#pragma unroll
    for (int j = 0; j < 8; ++j) v[j] = tile[sb * 8 + j][crow];
    *(u16x8*)(vT + (size_t)(bc * 64 + crow) * 4096 + bs * 64 + sb * 8) = v;
  }
}

// ---------------- 256x256 2-phase GEMM, counted vmcnt, FUSED RoPE epilogue --
// C[M,N] = A[M,K] @ B[N,K]^T, bf16 in / bf16 out (qkv projection).
// Main loop unchanged from r16. Epilogue: for q/k column-blocks (bn<10),
// rope pairs (d, d+64) live in adjacent waves (wn^1, same lane/i/j/r) ->
// 2-round LDS exchange through the (now dead) 128KB staging LDS, rope on
// unrounded f32 acc, single store. v-blocks (bn>=10) plain-store.
__global__ __launch_bounds__(512, 1) void k_gemm256(
    const unsigned short* __restrict__ A, const unsigned short* __restrict__ B,
    unsigned short* __restrict__ C, const float* __restrict__ cosb,
    const float* __restrict__ sinb, int K, int lda, int ldb, int ldc) {
  __shared__ unsigned short LDS[2][2][256 * 64];   // [buf][A/B] 128KB total
  const int t = threadIdx.x;                 // 0..511
  const int lane = t & 63, w = t >> 6;
  const int wm = w >> 2, wn = w & 3;         // 2 x 4 wave grid
  const int l15 = lane & 15, lq = lane >> 4;
  const int bn = blockIdx.x, bm = blockIdx.y;
  const unsigned short* Arow = A + (size_t)(bm * 256) * lda;
  const unsigned short* Brow = B + (size_t)(bn * 256) * ldb;
  const int NT = K >> 6;

  auto stage = [&](int buf, int kt, int q0, int q1) {
#pragma unroll
    for (int q = q0; q < q1; ++q) {
      int idx = (q & 3) * 512 + t;           // 0..2047
      int r = idx >> 3, blk = idx & 7;
      int sb = blk ^ (r & 7);
      const unsigned short* src =
          (q < 4 ? Arow + (size_t)r * lda : Brow + (size_t)r * ldb) + kt + sb * 8;
      unsigned short* dst = (q < 4 ? &LDS[buf][0][0] : &LDS[buf][1][0]) + (size_t)idx * 8;
      __builtin_amdgcn_global_load_lds(AS1(src), AS3(dst), 16, 0, 0);
    }
  };

  f32x4 acc[8][4] = {};
  stage(0, 0, 0, 8);                         // prologue: tile 0 (A+B)

  for (int tau = 0; tau < NT; ++tau) {
    const int buf = tau & 1;
    const char* Ab = (const char*)&LDS[buf][0][0];
    const char* Bb = (const char*)&LDS[buf][1][0];
    const bool pre = (tau + 1 < NT);
    // ---- phase 0: stage A(t+1); counted wait; B-frags; i-half 0 ----
    if (pre) stage(buf ^ 1, (tau + 1) << 6, 0, 4);
    if (pre) asm volatile("s_waitcnt vmcnt(4)" ::: "memory");
    else     asm volatile("s_waitcnt vmcnt(0)" ::: "memory");
    __builtin_amdgcn_s_barrier();

    bf16x8 bv[4][2];                         // wave's B fragments, held per tile
#pragma unroll
    for (int j = 0; j < 4; ++j)
#pragma unroll
      for (int kk = 0; kk < 2; ++kk) {
        int r = wn * 64 + j * 16 + l15;
        int off = (r * 128 + (kk * 32 + lq * 8) * 2) ^ ((r & 7) << 4);
        bv[j][kk] = *(const bf16x8*)(Bb + off);
      }
    __builtin_amdgcn_s_setprio(1);
#pragma unroll
    for (int i = 0; i < 4; ++i) {
      bf16x8 av[2];
#pragma unroll
      for (int kk = 0; kk < 2; ++kk) {
        int r = wm * 128 + i * 16 + l15;
        int off = (r * 128 + (kk * 32 + lq * 8) * 2) ^ ((r & 7) << 4);
        av[kk] = *(const bf16x8*)(Ab + off);
      }
#pragma unroll
      for (int kk = 0; kk < 2; ++kk)
#pragma unroll
        for (int j = 0; j < 4; ++j)
          acc[i][j] = __builtin_amdgcn_mfma_f32_16x16x32_bf16(av[kk], bv[j][kk], acc[i][j], 0, 0, 0);
    }
    __builtin_amdgcn_s_setprio(0);

    // ---- phase 1: stage B(t+1); i-half 1 ----
    if (pre) stage(buf ^ 1, (tau + 1) << 6, 4, 8);
    __builtin_amdgcn_s_setprio(1);
#pragma unroll
    for (int i = 4; i < 8; ++i) {
      bf16x8 av[2];
#pragma unroll
      for (int kk = 0; kk < 2; ++kk) {
        int r = wm * 128 + i * 16 + l15;
        int off = (r * 128 + (kk * 32 + lq * 8) * 2) ^ ((r & 7) << 4);
        av[kk] = *(const bf16x8*)(Ab + off);
      }
#pragma unroll
      for (int kk = 0; kk < 2; ++kk)
#pragma unroll
        for (int j = 0; j < 4; ++j)
          acc[i][j] = __builtin_amdgcn_mfma_f32_16x16x32_bf16(av[kk], bv[j][kk], acc[i][j], 0, 0, 0);
    }
    __builtin_amdgcn_s_setprio(0);
    __builtin_amdgcn_s_barrier();            // all reads of buf done before t+2 staging
  }

  // ---- epilogue ----
  if (bn < 10) {
    // q/k columns: fused RoPE. Partner (col^64) is wave wn^1, same lane/i/j/r.
    float* ex = (float*)&LDS[0][0][0];       // 128KB scratch (staging dead)
    const float sgn = (wn & 1) ? 1.f : -1.f; // upper half: +sin, lower: -sin
#pragma unroll
    for (int h = 0; h < 2; ++h) {            // 2 rounds over i-halves
      __builtin_amdgcn_s_barrier();          // prior round reads / K-loop done
#pragma unroll
      for (int i2 = 0; i2 < 4; ++i2)
#pragma unroll
        for (int j = 0; j < 4; ++j)
          *(f32x4*)&ex[(((w * 4 + i2) * 4 + j) << 8) + (lane << 2)] = acc[h * 4 + i2][j];
      __builtin_amdgcn_s_barrier();
#pragma unroll
      for (int i2 = 0; i2 < 4; ++i2) {
        int i = h * 4 + i2;
#pragma unroll
        for (int j = 0; j < 4; ++j) {
          f32x4 pv = *(const f32x4*)&ex[((((w ^ 1) * 4 + i2) * 4 + j) << 8) + (lane << 2)];
          int d0 = j * 16 + l15;             // own index mod 64 (tables duplicate)
          int n = bn * 256 + wn * 64 + j * 16 + l15;
#pragma unroll
          for (int r = 0; r < 4; ++r) {
            int m = bm * 256 + wm * 128 + i * 16 + lq * 4 + r;
            float cs = cosb[(size_t)m * 128 + d0];
            float sn = sinb[(size_t)m * 128 + d0];
            float v = acc[i][j][r] * cs + sgn * pv[r] * sn;
            C[(size_t)m * ldc + n] = f2b(v);
          }
        }
      }
    }
  } else {
    // v columns: plain store
#pragma unroll
    for (int i = 0; i < 8; ++i)
#pragma unroll
      for (int j = 0; j < 4; ++j)
#pragma unroll
        for (int r = 0; r < 4; ++r) {
          int m = bm * 256 + wm * 128 + i * 16 + lq * 4 + r;
          int n = bn * 256 + wn * 64 + j * 16 + l15;
          C[(size_t)m * ldc + n] = f2b(acc[i][j][r]);
        }
  }
}

// ---------------- GEMM C[M,N] = A[M,K] @ B[N,K]^T (128² proven; out-proj) --
template <int OUTF32>
__global__ __launch_bounds__(256) void k_gemm_bt(
    const unsigned short* __restrict__ A, const unsigned short* __restrict__ B,
    void* __restrict__ C, int K, int lda, int ldb, int ldc) {
  __shared__ unsigned short As[128 * 64];
  __shared__ unsigned short Bs[128 * 64];
  const int t = threadIdx.x;
  const int lane = t & 63, w = t >> 6;
  const int wm = w >> 1, wn = w & 1;
  const int bn = blockIdx.x, bm = blockIdx.y;
  const unsigned short* Arow = A + (size_t)(bm * 128) * lda;
  const unsigned short* Brow = B + (size_t)(bn * 128) * ldb;

  f32x4 acc[4][4] = {};
  for (int kt = 0; kt < K; kt += 64) {
#pragma unroll
    for (int i = 0; i < 4; ++i) {
      int idx = i * 256 + t;
      int r = idx >> 3, blk = idx & 7;
      int sb = blk ^ (r & 7);
      __builtin_amdgcn_global_load_lds(AS1(Arow + (size_t)r * lda + kt + sb * 8),
                                       AS3(As + (i * 256 + w * 64) * 8), 16, 0, 0);
    }
#pragma unroll
    for (int i = 0; i < 4; ++i) {
      int idx = i * 256 + t;
      int r = idx >> 3, blk = idx & 7;
      int sb = blk ^ (r & 7);
      __builtin_amdgcn_global_load_lds(AS1(Brow + (size_t)r * ldb + kt + sb * 8),
                                       AS3(Bs + (i * 256 + w * 64) * 8), 16, 0, 0);
    }
    __syncthreads();
#pragma unroll
    for (int kk = 0; kk < 2; ++kk) {
      bf16x8 av[4], bv[4];
#pragma unroll
      for (int i = 0; i < 4; ++i) {
        int r = wm * 64 + i * 16 + (lane & 15);
        int off = (r * 128 + (kk * 32 + (lane >> 4) * 8) * 2) ^ ((r & 7) << 4);
        av[i] = *(const bf16x8*)((const char*)As + off);
      }
#pragma unroll
      for (int j2 = 0; j2 < 4; ++j2) {
        int r = wn * 64 + j2 * 16 + (lane & 15);
        int off = (r * 128 + (kk * 32 + (lane >> 4) * 8) * 2) ^ ((r & 7) << 4);
        bv[j2] = *(const bf16x8*)((const char*)Bs + off);
      }
#pragma unroll
      for (int i = 0; i < 4; ++i)
#pragma unroll
        for (int j2 = 0; j2 < 4; ++j2)
          acc[i][j2] = __builtin_amdgcn_mfma_f32_16x16x32_bf16(av[i], bv[j2], acc[i][j2], 0, 0, 0);
    }
    __syncthreads();
  }
#pragma unroll
  for (int i = 0; i < 4; ++i)
#pragma unroll
    for (int j2 = 0; j2 < 4; ++j2)
#pragma unroll
      for (int r = 0; r < 4; ++r) {
        int m = bm * 128 + wm * 64 + i * 16 + (lane >> 4) * 4 + r;
        int n = bn * 128 + wn * 64 + j2 * 16 + (lane & 15);
        float v = acc[i][j2][r];
        if (OUTF32) ((float*)C)[(size_t)m * ldc + n] = v;
        else        ((unsigned short*)C)[(size_t)m * ldc + n] = f2b(v);
      }
}

// ---------------- attention staging helpers (r4/r10-proven) ----------------
__device__ __forceinline__ void stage_k(const unsigned short* __restrict__ qk,
                                        unsigned short* __restrict__ dst,
                                        int kt, int g, int t, int w) {
#pragma unroll
  for (int i = 0; i < 4; ++i) {   // K tile [64 keys][128 d], swz low 3 bits of col16
    int idx = i * 256 + t;
    int r = idx >> 4, blk = idx & 15;
    int sb = (blk & 8) | ((blk ^ r) & 7);
    __builtin_amdgcn_global_load_lds(
        AS1(qk + (size_t)(kt * 64 + r) * 3072 + 2048 + g * 128 + sb * 8),
        AS3(dst + (i * 256 + w * 64) * 8), 16, 0, 0);
  }
}
__device__ __forceinline__ void stage_v(const unsigned short* __restrict__ vT,
                                        unsigned short* __restrict__ dst,
                                        int kt, int g, int t, int w) {
#pragma unroll
  for (int i = 0; i < 4; ++i) {   // V^T tile [128 d][64 keys]
    int idx = i * 256 + t;
    int r = idx >> 3, blk = idx & 7;
    int sb = blk ^ (r & 7);
    __builtin_amdgcn_global_load_lds(
        AS1(vT + (size_t)(g * 128 + r) * 4096 + kt * 64 + sb * 8),
        AS3(dst + (i * 256 + w * 64) * 8), 16, 0, 0);
  }
}

// ---------------- fused causal GQA flash attention (r13, best) ----------------
__global__ __launch_bounds__(512, 1) void k_attn(const unsigned short* __restrict__ qk,
                                                 const unsigned short* __restrict__ vT,
                                                 unsigned short* __restrict__ ctx) {
  __shared__ unsigned short Ks[2][2][64 * 128];   // [group][parity]
  __shared__ unsigned short Vs[2][2][64 * 128];
  const int b = blockIdx.x >> 3;             // 0..31
  const int hp = blockIdx.x & 7;             // head pair: heads 2hp, 2hp+1
  const int h0 = hp * 2, g = hp >> 1;
  const int t = threadIdx.x;                 // 0..511
  const int grp = t >> 8;                    // 0 = keys low half, 1 = high half
  const int tg = t & 255;                    // thread within group
  const int lane = t & 63, w4 = (t >> 6) & 3;
  const int l15 = lane & 15, lq = lane >> 4;

  float* ol = (float*)&Ks[0][0][0];          // 64KB combine scratch (post-loop)
  float* ll = (float*)&Vs[0][0][0];          // lsum scratch (post-loop)

  for (int ph = 0; ph < 2; ++ph) {
    const int qt = ph ? 63 - b : b;
    const int ntot = qt + 1;
    const int m = (ntot + 1) >> 1;           // group A tiles [0,m)
    const int nB = ntot - m;                 // group B tiles [m,ntot), nB <= m
    const int kbase = grp ? m : 0;
    const int ntile = grp ? nB : m;
    const int qg = qt * 64 + w4 * 16 + l15;  // this lane's softmax q-row

    bf16x8 aq0[4], aq1[4];        // Q fragments, both heads
    {
      const unsigned short* qb =
          qk + (size_t)(qt * 64 + w4 * 16 + l15) * 3072 + h0 * 128 + lq * 8;
#pragma unroll
      for (int sl = 0; sl < 4; ++sl) {
        aq0[sl] = *(const bf16x8*)(qb + sl * 32);
        aq1[sl] = *(const bf16x8*)(qb + 128 + sl * 32);
      }
    }
    f32x4 o0[8] = {}, o1[8] = {};
    float lsum0 = 0.f, lsum1 = 0.f;

    unsigned short* K0 = Ks[grp][0];
    unsigned short* K1 = Ks[grp][1];
    unsigned short* V0 = Vs[grp][0];
    unsigned short* V1 = Vs[grp][1];

    if (ntile > 0) {                         // prologue: stage my first tile
      stage_k(qk, K0, kbase, g, tg, w4);
      stage_v(vT, V0, kbase, g, tg, w4);
    }
    asm volatile("s_waitcnt vmcnt(0)" ::: "memory");
    __builtin_amdgcn_s_barrier();

    auto tile = [&](const unsigned short* Kb, const unsigned short* Vb,
                    int kt, bool maskT) {
      f32x4 st0[4] = {}, st1[4] = {};
      __builtin_amdgcn_s_setprio(1);
#pragma unroll
      for (int sl = 0; sl < 4; ++sl)
#pragma unroll
        for (int nt = 0; nt < 4; ++nt) {
          int key = nt * 16 + l15;
          int off = (key * 256 + sl * 64 + lq * 16) ^ ((key & 7) << 4);
          bf16x8 bk = *(const bf16x8*)((const char*)Kb + off);
          st0[nt] = __builtin_amdgcn_mfma_f32_16x16x32_bf16(bk, aq0[sl], st0[nt], 0, 0, 0);
          st1[nt] = __builtin_amdgcn_mfma_f32_16x16x32_bf16(bk, aq1[sl], st1[nt], 0, 0, 0);
        }
      __builtin_amdgcn_s_setprio(0);

      bf16x4 pa0[4], pa1[4];
#pragma unroll
      for (int nt = 0; nt < 4; ++nt)
#pragma unroll
        for (int r = 0; r < 4; ++r) {
          float p0 = __builtin_amdgcn_exp2f(st0[nt][r]);
          float p1 = __builtin_amdgcn_exp2f(st1[nt][r]);
          if (maskT) {
            int key = kt * 64 + nt * 16 + lq * 4 + r;
            if (key > qg) { p0 = 0.f; p1 = 0.f; }
          }
          lsum0 += p0; lsum1 += p1;
          unsigned int u0 = __builtin_bit_cast(unsigned int, p0) + 0x8000u;
          unsigned int u1 = __builtin_bit_cast(unsigned int, p1) + 0x8000u;
          pa0[nt][r] = (short)(u0 >> 16);
          pa1[nt][r] = (short)(u1 >> 16);
        }

      __builtin_amdgcn_s_setprio(1);
#pragma unroll
      for (int nt = 0; nt < 4; ++nt)
#pragma unroll
        for (int dt = 0; dt < 8; ++dt) {
          int d = dt * 16 + l15;
          int off = (d * 128 + nt * 32 + lq * 8) ^ ((d & 7) << 4);
          bf16x4 vv = *(const bf16x4*)((const char*)Vb + off);
          o0[dt] = mfma16x16x16(pa0[nt], vv, o0[dt]);
          o1[dt] = mfma16x16x16(pa1[nt], vv, o1[dt]);
        }
      __builtin_amdgcn_s_setprio(0);
    };

    for (int i = 0; i < m; ++i) {            // both groups run m iterations
      const int cur = i & 1;
      if (i + 1 < ntile) {                   // prefetch my next tile
        stage_k(qk, cur ? K0 : K1, kbase + i + 1, g, tg, w4);
        stage_v(vT, cur ? V0 : V1, kbase + i + 1, g, tg, w4);
      }
      if (i < ntile) {
        const int kt = kbase + i;
        tile(cur ? K1 : K0, cur ? V1 : V0, kt, kt == qt);
      }
      asm volatile("s_waitcnt vmcnt(0)" ::: "memory");
      __builtin_amdgcn_s_barrier();          // also fences K/V reads for reuse
    }

    // ---- combine: O = (O_A + O_B) / (l_A + l_B) via LDS ----
    float f0 = lsum0, f1 = lsum1;            // reduce partial row sums
    f0 += __shfl_xor(f0, 16); f0 += __shfl_xor(f0, 32);
    f1 += __shfl_xor(f1, 16); f1 += __shfl_xor(f1, 32);

    if (grp == 1) {                          // B publishes partials
#pragma unroll
      for (int dt = 0; dt < 8; ++dt)
#pragma unroll
        for (int r = 0; r < 4; ++r) {
          ol[(dt * 4 + r) * 256 + tg]        = o0[dt][r];
          ol[(32 + dt * 4 + r) * 256 + tg]   = o1[dt][r];
        }
      if (lq == 0) {
        ll[w4 * 16 + l15]      = f0;
        ll[64 + w4 * 16 + l15] = f1;
      }
    }
    __builtin_amdgcn_s_barrier();
    if (grp == 0) {                          // A combines, normalizes, stores
#pragma unroll
      for (int dt = 0; dt < 8; ++dt)
#pragma unroll
        for (int r = 0; r < 4; ++r) {
          o0[dt][r] += ol[(dt * 4 + r) * 256 + tg];
          o1[dt][r] += ol[(32 + dt * 4 + r) * 256 + tg];
        }
      f0 += ll[w4 * 16 + l15];
      f1 += ll[64 + w4 * 16 + l15];
      float iq0[4], iq1[4];
#pragma unroll
      for (int r = 0; r < 4; ++r) {
        iq0[r] = 1.f / __shfl(f0, lq * 4 + r);
        iq1[r] = 1.f / __shfl(f1, lq * 4 + r);
      }
#pragma unroll
      for (int dt = 0; dt < 8; ++dt)
#pragma unroll
        for (int r = 0; r < 4; ++r) {
          int q = qt * 64 + w4 * 16 + lq * 4 + r;
          int c = h0 * 128 + dt * 16 + l15;
          ctx[(size_t)q * 2048 + c]       = f2b(o0[dt][r] * iq0[r]);
          ctx[(size_t)q * 2048 + c + 128] = f2b(o1[dt][r] * iq1[r]);
        }
    }
    __builtin_amdgcn_s_barrier();            // protect LDS for next phase
  }
}

// ---------------- host ----------------
extern "C" void kernel_launch(void* const* d_in, const int* in_sizes, int n_in,
                              void* d_out, int out_size, void* d_ws, size_t ws_size,
                              hipStream_t stream) {
  const float* x    = (const float*)d_in[0];
  const float* cosb = (const float*)d_in[2];
  const float* sinb = (const float*)d_in[3];
  const float* Wq   = (const float*)d_in[4];
  const float* Wk   = (const float*)d_in[5];
  const float* Wv   = (const float*)d_in[6];
  const float* Wo   = (const float*)d_in[7];

  char* p = (char*)d_ws;
  unsigned short* xb   = (unsigned short*)p; p += (size_t)8388608 * 2;   // x bf16
  unsigned short* wqkv = (unsigned short*)p; p += (size_t)6291456 * 2;   // [3072][2048]
  unsigned short* Wob  = (unsigned short*)p; p += (size_t)4194304 * 2;
  unsigned short* qkvb = (unsigned short*)p; p += (size_t)4096 * 3072 * 2;
  unsigned short* vTb  = (unsigned short*)p; p += (size_t)512 * 4096 * 2;
  unsigned short* ctx  = (unsigned short*)p; p += (size_t)4096 * 2048 * 2;
  if (ws_size < (size_t)(p - (char*)d_ws)) return;

  const float SC = 0.12751741f;   // (1/sqrt(128)) * log2(e), folded into Wq

  k_cvt_all<<<9216, 256, 0, stream>>>(x, Wq, Wk, Wv, Wo, xb, wqkv, Wob, SC);

  // qkv = x @ [Wq;Wk;Wv]^T -> [4096][3072], RoPE fused in epilogue (q/k cols)
  k_gemm256<<<dim3(12, 16), 512, 0, stream>>>(xb, wqkv, qkvb, cosb, sinb,
                                              2048, 2048, 2048, 3072);

  k_tr<<<512, 256, 0, stream>>>(qkvb, vTb);

  k_attn<<<256, 512, 0, stream>>>(qkvb, vTb, ctx);

  k_gemm_bt<1><<<dim3(16, 32), 256, 0, stream>>>(ctx, Wob, d_out, 2048, 2048, 2048, 2048);
}